// Round 2
// baseline (791.634 us; speedup 1.0000x reference)
//
#include <hip/hip_runtime.h>
#include <hip/hip_bf16.h>

// LinAtten: x[4,4096,1024] -> qkv GEMM -> elu+1 -> linear attention -> proj GEMM.
// Plain-bf16 MFMA GEMMs (error budget ~20x under threshold), batch-chunked
// pipeline to fit a small workspace (43 MB; 34.6 MB floor with qp->d_out).

#define DIM    1024
#define HEADS  16
#define SEQ    4096
#define CHROWS 4096              // rows per batch chunk

typedef __attribute__((ext_vector_type(8))) short bf16x8;
typedef __attribute__((ext_vector_type(4))) float f32x4;

__device__ __forceinline__ unsigned short f2bf(float f) {
  unsigned u = __float_as_uint(f);
  u += 0x7fffu + ((u >> 16) & 1u);          // RNE
  return (unsigned short)(u >> 16);
}
__device__ __forceinline__ float bf2f(unsigned short h) {
  return __uint_as_float((unsigned)h << 16);
}

__device__ __forceinline__ void gload_lds16(const void* g, void* l) {
  __builtin_amdgcn_global_load_lds((const __attribute__((address_space(1))) void*)g,
                                   (__attribute__((address_space(3))) void*)l, 16, 0, 0);
}

// ---------------- conversions ----------------

// one batch chunk of x: [4096,1024] f32 -> bf16
__global__ __launch_bounds__(256) void conv_x(const float* __restrict__ x,
                                              unsigned short* __restrict__ Ax) {
  int idx = blockIdx.x * 256 + threadIdx.x;       // float4 index, 1,048,576 total
  float4 v = ((const float4*)x)[idx];
  ushort4 h;
  h.x = f2bf(v.x); h.y = f2bf(v.y); h.z = f2bf(v.z); h.w = f2bf(v.w);
  ((ushort4*)Ax)[idx] = h;
}

// W [1024, Ncols] f32 -> Bt [Ncols][1024] bf16 (transpose via LDS tile)
__global__ __launch_bounds__(256) void conv_w(const float* __restrict__ W,
                                              unsigned short* __restrict__ Bt,
                                              int Ncols) {
  __shared__ float tile[64][65];
  const int kk0 = blockIdx.x * 64;
  const int c0  = blockIdx.y * 64;
  const int t = threadIdx.x;
  const int cl = t & 63, kl = t >> 6;             // kl 0..3
#pragma unroll
  for (int i = 0; i < 16; ++i)
    tile[kl + i * 4][cl] = W[(long)(kk0 + kl + i * 4) * Ncols + c0 + cl];
  __syncthreads();
#pragma unroll
  for (int i = 0; i < 16; ++i) {
    int c = kl + i * 4;                            // local col 0..63
    Bt[(long)(c0 + c) * 1024 + kk0 + cl] = f2bf(tile[cl][c]);
  }
}

// ---------------- bf16 MFMA GEMM (m97 structure: 128x128 tile, BK=32, K=1024) ---
// A [4096][1024] bf16 row-major, Bt [N][1024] bf16 (B transposed).
// EPI 0: route cols to q/k/v planes (elu+1 on q,k), bf16 out.
// EPI 1: + bias, f32 out.
template <int EPI>
__global__ __launch_bounds__(256) void gemm_bt(const unsigned short* __restrict__ A,
                                               const unsigned short* __restrict__ Bt,
                                               unsigned short* __restrict__ P0,
                                               unsigned short* __restrict__ P1,
                                               unsigned short* __restrict__ P2,
                                               float* __restrict__ Cf,
                                               const float* __restrict__ bias) {
  __shared__ unsigned short As[128 * 32];   // [row][k], 8KB
  __shared__ unsigned short Bs[128 * 32];   // [col][k], 8KB
  const int t = threadIdx.x;
  const int lane = t & 63;
  const int w = t >> 6;
  const int wr = w >> 1, wc = w & 1;        // 2x2 wave grid, 64x64 per wave
  const int m0 = blockIdx.y * 128;
  const int c0 = blockIdx.x * 128;
  const int K = 1024;

  f32x4 acc[4][4] = {};

  const int li0 = w * 128 + lane;
  const int li1 = li0 + 64;
  const unsigned short* a0 = A + (long)(m0 + (li0 >> 2)) * K + (li0 & 3) * 8;
  const unsigned short* a1 = A + (long)(m0 + (li1 >> 2)) * K + (li1 & 3) * 8;
  const unsigned short* b0 = Bt + (long)(c0 + (li0 >> 2)) * K + (li0 & 3) * 8;
  const unsigned short* b1 = Bt + (long)(c0 + (li1 >> 2)) * K + (li1 & 3) * 8;
  unsigned short* asd0 = &As[li0 * 8];
  unsigned short* asd1 = &As[li1 * 8];
  unsigned short* bsd0 = &Bs[li0 * 8];
  unsigned short* bsd1 = &Bs[li1 * 8];

  const int aoff = (wr * 64 + (lane & 15)) * 32 + (lane >> 4) * 8;
  const int boff = (wc * 64 + (lane & 15)) * 32 + (lane >> 4) * 8;

  for (int k0 = 0; k0 < K; k0 += 32) {
    gload_lds16(a0 + k0, asd0);
    gload_lds16(a1 + k0, asd1);
    gload_lds16(b0 + k0, bsd0);
    gload_lds16(b1 + k0, bsd1);
    __syncthreads();
    bf16x8 af[4], bfr[4];
#pragma unroll
    for (int mi = 0; mi < 4; ++mi) af[mi] = *(const bf16x8*)&As[aoff + mi * 16 * 32];
#pragma unroll
    for (int ni = 0; ni < 4; ++ni) bfr[ni] = *(const bf16x8*)&Bs[boff + ni * 16 * 32];
#pragma unroll
    for (int mi = 0; mi < 4; ++mi)
#pragma unroll
      for (int ni = 0; ni < 4; ++ni)
        acc[mi][ni] = __builtin_amdgcn_mfma_f32_16x16x32_bf16(af[mi], bfr[ni],
                                                              acc[mi][ni], 0, 0, 0);
    __syncthreads();
  }

  // C/D layout (m89-verified): col = lane&15, row = (lane>>4)*4 + j
  const int rowb = m0 + wr * 64 + (lane >> 4) * 4;
  if (EPI == 0) {
    const int p = (c0 + wc * 64) >> 10;           // wave-uniform plane 0..2
    unsigned short* P = (p == 0) ? P0 : (p == 1) ? P1 : P2;
    const int ccb = ((c0 + wc * 64) & 1023) + (lane & 15);
#pragma unroll
    for (int mi = 0; mi < 4; ++mi)
#pragma unroll
      for (int ni = 0; ni < 4; ++ni)
#pragma unroll
        for (int j = 0; j < 4; ++j) {
          int r = rowb + mi * 16 + j;
          int cc = ccb + ni * 16;
          float v = acc[mi][ni][j];
          if (p < 2) v = (v > 0.f) ? v + 1.f : __expf(v);   // elu + 1
          P[(long)r * 1024 + cc] = f2bf(v);
        }
  } else {
    const int cb = c0 + wc * 64 + (lane & 15);
#pragma unroll
    for (int mi = 0; mi < 4; ++mi)
#pragma unroll
      for (int ni = 0; ni < 4; ++ni)
#pragma unroll
        for (int j = 0; j < 4; ++j) {
          int r = rowb + mi * 16 + j;
          int c = cb + ni * 16;
          Cf[(long)r * 1024 + c] = acc[mi][ni][j] + bias[c];
        }
  }
}

// ---------------- attention pass 1 (per batch): kv[h][d][e], ksum[h][d] --------
__global__ __launch_bounds__(256) void attn_kv(const unsigned short* __restrict__ kp,
                                               const unsigned short* __restrict__ vp,
                                               float* __restrict__ kvg,
                                               float* __restrict__ ksumg) {
  const int chunk = blockIdx.x;    // 16 chunks of 256 rows
  const int h = blockIdx.y;
  const int t = threadIdx.x;
  const int d0 = (t >> 4) * 4;
  const int e0 = (t & 15) * 4;
  __shared__ float kt[32][64];
  __shared__ float vt[32][64];
  float kvloc[4][4] = {};
  float ksumloc = 0.f;
  const int rowbase = chunk * 256;
  for (int s = 0; s < 8; ++s) {
    __syncthreads();
#pragma unroll
    for (int i = 0; i < 2; ++i) {
      int idx = i * 256 + t;        // 0..511 = 32 rows x 16 col-groups
      int r = idx >> 4, c4 = (idx & 15) * 4;
      long o = (long)(rowbase + s * 32 + r) * 1024 + h * 64 + c4;
      ushort4 kk = *(const ushort4*)&kp[o];
      ushort4 vv = *(const ushort4*)&vp[o];
      *(float4*)&kt[r][c4] = make_float4(bf2f(kk.x), bf2f(kk.y), bf2f(kk.z), bf2f(kk.w));
      *(float4*)&vt[r][c4] = make_float4(bf2f(vv.x), bf2f(vv.y), bf2f(vv.z), bf2f(vv.w));
    }
    __syncthreads();
    for (int nn = 0; nn < 32; ++nn) {
      const float4 kf = *(const float4*)&kt[nn][d0];
      const float4 vf = *(const float4*)&vt[nn][e0];
      float ka[4] = {kf.x, kf.y, kf.z, kf.w};
      float va[4] = {vf.x, vf.y, vf.z, vf.w};
#pragma unroll
      for (int i = 0; i < 4; ++i)
#pragma unroll
        for (int j = 0; j < 4; ++j) kvloc[i][j] += ka[i] * va[j];
      if (t < 64) ksumloc += kt[nn][t];
    }
  }
  float* kvdst = kvg + h * 4096;
#pragma unroll
  for (int i = 0; i < 4; ++i)
#pragma unroll
    for (int j = 0; j < 4; ++j)
      atomicAdd(&kvdst[(d0 + i) * 64 + e0 + j], kvloc[i][j]);
  if (t < 64) atomicAdd(&ksumg[h * 64 + t], ksumloc);
}

// ---------------- attention pass 2 (per batch): out = (q@kv)/(q.ksum+1e-6) -----
__global__ __launch_bounds__(256) void attn_out(const unsigned short* __restrict__ qp,
                                                const float* __restrict__ kvg,
                                                const float* __restrict__ ksumg,
                                                unsigned short* __restrict__ Aout) {
  const int nc = blockIdx.x;       // 64-row chunk (64 chunks)
  const int h = blockIdx.y;
  const int t = threadIdx.x;
  const int e = t & 63, nl = t >> 6;
  __shared__ float kvs[64 * 64];
  __shared__ float ksums[64];
  __shared__ float qs[4][64];
  {
    const float* src = kvg + h * 4096;
#pragma unroll
    for (int i = 0; i < 4; ++i) {
      int idx = i * 256 + t;
      *(float4*)&kvs[idx * 4] = ((const float4*)src)[idx];
    }
    if (t < 64) ksums[t] = ksumg[h * 64 + t];
  }
  const int rowbase = nc * 64;
  for (int g = 0; g < 16; ++g) {
    __syncthreads();
    if (t < 64) {
      int r = t >> 4, c4 = (t & 15) * 4;
      ushort4 qq = *(const ushort4*)&qp[(long)(rowbase + g * 4 + r) * 1024 + h * 64 + c4];
      *(float4*)&qs[r][c4] = make_float4(bf2f(qq.x), bf2f(qq.y), bf2f(qq.z), bf2f(qq.w));
    }
    __syncthreads();
    float num = 0.f, den = 0.f;
#pragma unroll
    for (int d = 0; d < 64; ++d) {
      float qd = qs[nl][d];
      num += qd * kvs[d * 64 + e];
      den += qd * ksums[d];
    }
    float o = num / (den + 1e-6f);
    Aout[(long)(rowbase + g * 4 + nl) * 1024 + h * 64 + e] = f2bf(o);
  }
}

// ---------------- launch ----------------

extern "C" void kernel_launch(void* const* d_in, const int* in_sizes, int n_in,
                              void* d_out, int out_size, void* d_ws, size_t ws_size,
                              hipStream_t stream) {
  const float* x     = (const float*)d_in[0];
  const float* Wqkv  = (const float*)d_in[1];
  const float* Wproj = (const float*)d_in[2];
  const float* bproj = (const float*)d_in[3];

  const size_t SZ_BT1   = 3072UL * 1024 * 2;   //  6,291,456
  const size_t SZ_BT2   = 1024UL * 1024 * 2;   //  2,097,152
  const size_t SZ_PLANE = 4096UL * 1024 * 2;   //  8,388,608
  const size_t SZ_KV    = 64UL * 64 * 64 * 4;  //  1,048,576
  const size_t SZ_KSUM  = 64UL * 64 * 4;       //     16,384

  size_t off = 0;
  char* ws = (char*)d_ws;
  unsigned short* Bt1 = (unsigned short*)(ws + off); off += SZ_BT1;
  unsigned short* Bt2 = (unsigned short*)(ws + off); off += SZ_BT2;
  unsigned short* Ax  = (unsigned short*)(ws + off); off += SZ_PLANE;  // reused as Aout
  unsigned short* Kp  = (unsigned short*)(ws + off); off += SZ_PLANE;
  unsigned short* Vp  = (unsigned short*)(ws + off); off += SZ_PLANE;
  float*          kvg = (float*)(ws + off);          off += SZ_KV;
  float*          ksm = (float*)(ws + off);          off += SZ_KSUM;
  const size_t BASE_NEED = off;                       // 34,619,392 (~33 MiB)
  const bool qp_in_ws = (ws_size >= BASE_NEED + SZ_PLANE);
  unsigned short* Qp_ws = (unsigned short*)(ws + off);
  if (!qp_in_ws && ws_size < BASE_NEED) return;       // truly insufficient scratch

  hipMemsetAsync(kvg, 0, SZ_KV + SZ_KSUM, stream);    // kv + ksum accumulators

  conv_w<<<dim3(16, 48), 256, 0, stream>>>(Wqkv, Bt1, 3072);
  conv_w<<<dim3(16, 16), 256, 0, stream>>>(Wproj, Bt2, 1024);

  for (int b = 0; b < 4; ++b) {
    const float* xb = x + (size_t)b * CHROWS * DIM;
    float* outb = (float*)d_out + (size_t)b * CHROWS * DIM;
    // qp fallback: stash q (bf16) in d_out's batch-b region; dead before gemm2(b)
    unsigned short* Qp = qp_in_ws ? Qp_ws : (unsigned short*)outb;
    float* kvb = kvg + (size_t)b * HEADS * 4096;
    float* ksb = ksm + (size_t)b * HEADS * 64;

    conv_x<<<dim3(4096), 256, 0, stream>>>(xb, Ax);
    gemm_bt<0><<<dim3(24, 32), 256, 0, stream>>>(Ax, Bt1, Qp, Kp, Vp, nullptr, nullptr);
    attn_kv<<<dim3(16, HEADS), 256, 0, stream>>>(Kp, Vp, kvb, ksb);
    attn_out<<<dim3(64, HEADS), 256, 0, stream>>>(Qp, kvb, ksb, Ax);
    gemm_bt<1><<<dim3(8, 32), 256, 0, stream>>>(Ax, Bt2, nullptr, nullptr, nullptr,
                                                outb, bproj);
  }
}

// Round 4
// 592.173 us; speedup vs baseline: 1.3368x; 1.3368x over previous
//
#include <hip/hip_runtime.h>
#include <hip/hip_bf16.h>

// LinAtten: x[4,4096,1024] -> qkv GEMM -> elu+1 -> linear attention -> proj GEMM.
// bf16 MFMA GEMMs on the 256^2 8-phase schedule (T2 swizzle + T3/T4 counted
// vmcnt + T5 setprio). Adaptive batch-chunking by ws_size; Q plane lives in
// d_out's (dead) chunk region.

#define DIM    1024
#define HEADS  16
#define SEQ    4096

typedef __attribute__((ext_vector_type(8))) short bf16x8;
typedef __attribute__((ext_vector_type(4))) float f32x4;

__device__ __forceinline__ unsigned short f2bf(float f) {
  unsigned u = __float_as_uint(f);
  u += 0x7fffu + ((u >> 16) & 1u);          // RNE
  return (unsigned short)(u >> 16);
}
__device__ __forceinline__ float bf2f(unsigned short h) {
  return __uint_as_float((unsigned)h << 16);
}
__device__ __forceinline__ void gload_lds16(const void* g, void* l) {
  __builtin_amdgcn_global_load_lds((const __attribute__((address_space(1))) void*)g,
                                   (__attribute__((address_space(3))) void*)l, 16, 0, 0);
}

// ---------------- conversions ----------------

__global__ __launch_bounds__(256) void conv_x(const float* __restrict__ x,
                                              unsigned short* __restrict__ Ax) {
  int idx = blockIdx.x * 256 + threadIdx.x;       // float4 index
  float4 v = ((const float4*)x)[idx];
  ushort4 h;
  h.x = f2bf(v.x); h.y = f2bf(v.y); h.z = f2bf(v.z); h.w = f2bf(v.w);
  ((ushort4*)Ax)[idx] = h;
}

// W [1024, Ncols] f32 -> Bt [Ncols][1024] bf16 (transpose via LDS tile)
__global__ __launch_bounds__(256) void conv_w(const float* __restrict__ W,
                                              unsigned short* __restrict__ Bt,
                                              int Ncols) {
  __shared__ float tile[64][65];
  const int kk0 = blockIdx.x * 64;
  const int c0  = blockIdx.y * 64;
  const int t = threadIdx.x;
  const int cl = t & 63, kl = t >> 6;
#pragma unroll
  for (int i = 0; i < 16; ++i)
    tile[kl + i * 4][cl] = W[(long)(kk0 + kl + i * 4) * Ncols + c0 + cl];
  __syncthreads();
#pragma unroll
  for (int i = 0; i < 16; ++i) {
    int c = kl + i * 4;
    Bt[(long)(c0 + c) * 1024 + kk0 + cl] = f2bf(tile[cl][c]);
  }
}

// ---------------- 256^2 8-phase bf16 GEMM --------------------------------------
// A [M][1024] bf16, Bt [N][1024] bf16. 512 thr = 8 waves (2M x 4N), per-wave
// out 128x64. LDS 128KB: P in {0,1}: bufA(P)=P*32768, bufB(P)=P*32768+16384
// (ushort idx); halves of 128 rows x 64 k; row r slot s at r*64 + s*8, with
// XOR swizzle: content slot s holds global k-slot s^(r&7)  (write side via
// pre-swizzled global source; gload dest linear).

__device__ __forceinline__ void stage_half(const unsigned short* srcBase, long rowOff,
                                           int kt, unsigned short* ldsBase, int t) {
  const unsigned short* s0 = srcBase + rowOff + (long)kt * 64;
  gload_lds16(s0, ldsBase + t * 8);                      // rows H*128 + 0..63
  gload_lds16(s0 + 64 * 1024, ldsBase + 4096 + t * 8);   // rows H*128 + 64..127
}

#define MF(a, b, c) __builtin_amdgcn_mfma_f32_16x16x32_bf16(a, b, c, 0, 0, 0)

// One phase: ds-read A-quad (+B all if qd==0) from buffer P, issue STAGE,
// optional WAIT, barrier, MFMA quadrant, barrier.
#define PHASE(P, qd, READB, STAGE, WAIT)                                          \
  {                                                                               \
    const unsigned short* ab = &lds[(P) * 32768 + abase + (qd) * 2048];           \
    bf16x8 a00 = *(const bf16x8*)(ab + sl0);                                      \
    bf16x8 a01 = *(const bf16x8*)(ab + sl1);                                      \
    bf16x8 a10 = *(const bf16x8*)(ab + 1024 + sl0);                               \
    bf16x8 a11 = *(const bf16x8*)(ab + 1024 + sl1);                               \
    if (READB) {                                                                  \
      const unsigned short* bb = &lds[(P) * 32768 + 16384 + bbase];               \
      bfr[0][0] = *(const bf16x8*)(bb + sl0);                                     \
      bfr[0][1] = *(const bf16x8*)(bb + sl1);                                     \
      bfr[1][0] = *(const bf16x8*)(bb + 1024 + sl0);                              \
      bfr[1][1] = *(const bf16x8*)(bb + 1024 + sl1);                              \
      bfr[2][0] = *(const bf16x8*)(bb + 2048 + sl0);                              \
      bfr[2][1] = *(const bf16x8*)(bb + 2048 + sl1);                              \
      bfr[3][0] = *(const bf16x8*)(bb + 3072 + sl0);                              \
      bfr[3][1] = *(const bf16x8*)(bb + 3072 + sl1);                              \
    }                                                                             \
    STAGE;                                                                        \
    WAIT;                                                                         \
    asm volatile("s_barrier" ::: "memory");                                       \
    __builtin_amdgcn_s_setprio(1);                                                \
    acc[(qd)*2][0] = MF(a00, bfr[0][0], acc[(qd)*2][0]);                          \
    acc[(qd)*2][1] = MF(a00, bfr[1][0], acc[(qd)*2][1]);                          \
    acc[(qd)*2][2] = MF(a00, bfr[2][0], acc[(qd)*2][2]);                          \
    acc[(qd)*2][3] = MF(a00, bfr[3][0], acc[(qd)*2][3]);                          \
    acc[(qd)*2][0] = MF(a01, bfr[0][1], acc[(qd)*2][0]);                          \
    acc[(qd)*2][1] = MF(a01, bfr[1][1], acc[(qd)*2][1]);                          \
    acc[(qd)*2][2] = MF(a01, bfr[2][1], acc[(qd)*2][2]);                          \
    acc[(qd)*2][3] = MF(a01, bfr[3][1], acc[(qd)*2][3]);                          \
    acc[(qd)*2+1][0] = MF(a10, bfr[0][0], acc[(qd)*2+1][0]);                      \
    acc[(qd)*2+1][1] = MF(a10, bfr[1][0], acc[(qd)*2+1][1]);                      \
    acc[(qd)*2+1][2] = MF(a10, bfr[2][0], acc[(qd)*2+1][2]);                      \
    acc[(qd)*2+1][3] = MF(a10, bfr[3][0], acc[(qd)*2+1][3]);                      \
    acc[(qd)*2+1][0] = MF(a11, bfr[0][1], acc[(qd)*2+1][0]);                      \
    acc[(qd)*2+1][1] = MF(a11, bfr[1][1], acc[(qd)*2+1][1]);                      \
    acc[(qd)*2+1][2] = MF(a11, bfr[2][1], acc[(qd)*2+1][2]);                      \
    acc[(qd)*2+1][3] = MF(a11, bfr[3][1], acc[(qd)*2+1][3]);                      \
    __builtin_amdgcn_s_setprio(0);                                                \
    asm volatile("s_barrier" ::: "memory");                                       \
  }

#define VM4 asm volatile("s_waitcnt vmcnt(4)" ::: "memory")
#define VM0 asm volatile("s_waitcnt vmcnt(0)" ::: "memory")

// EPI 0: write q/k/v planes (elu+1 on q,k), bf16.  EPI 1: +bias, f32.
template <int EPI>
__global__ __launch_bounds__(512) void gemm8(const unsigned short* __restrict__ A,
                                             const unsigned short* __restrict__ Bt,
                                             unsigned short* __restrict__ P0,
                                             unsigned short* __restrict__ P1,
                                             unsigned short* __restrict__ P2,
                                             float* __restrict__ Cf,
                                             const float* __restrict__ bias) {
  __shared__ unsigned short lds[65536];     // 128 KiB
  const int t = threadIdx.x;
  const int l = t & 63, w = t >> 6;
  const int wr = w >> 2, wc = w & 3;        // 2x4 wave grid
  const int m0 = blockIdx.y * 256;
  const int c0 = blockIdx.x * 256;

  f32x4 acc[8][4] = {};
  bf16x8 bfr[4][2];

  // ds_read address components (swizzle key r&7 == l&7 since frag rows are 16-aligned)
  const int sl0 = (((l >> 4)) ^ (l & 7)) * 8;
  const int sl1 = ((4 + (l >> 4)) ^ (l & 7)) * 8;
  const int abase = wr * 8192 + (l & 15) * 64;
  const int bbase = (wc >> 1) * 8192 + (wc & 1) * 4096 + (l & 15) * 64;

  // staging source (pre-swizzled global k-slot)
  const int sw = ((t & 7) ^ ((t >> 3) & 7)) * 8;
  const unsigned short* srcA = A + (long)(m0 + (t >> 3)) * 1024 + sw;
  const unsigned short* srcB = Bt + (long)(c0 + (t >> 3)) * 1024 + sw;
  const long H1 = 128L * 1024;              // +128 rows

  // LDS half bases (ushort idx)
  unsigned short* A0h0 = &lds[0];      unsigned short* A0h1 = &lds[8192];
  unsigned short* B0h0 = &lds[16384];  unsigned short* B0h1 = &lds[24576];
  unsigned short* A1h0 = &lds[32768];  unsigned short* A1h1 = &lds[40960];
  unsigned short* B1h0 = &lds[49152];  unsigned short* B1h1 = &lds[57344];

  // prologue: T0 -> P0 (A,B); T1 B -> P1
  stage_half(srcA, 0,  0, A0h0, t);  stage_half(srcA, H1, 0, A0h1, t);
  stage_half(srcB, 0,  0, B0h0, t);  stage_half(srcB, H1, 0, B0h1, t);
  stage_half(srcB, 0,  1, B1h0, t);  stage_half(srcB, H1, 1, B1h1, t);
  VM4;
  asm volatile("s_barrier" ::: "memory");

  for (int it = 0; it < 7; ++it) {          // tiles 2it,2it+1; prefetch 2it+2,2it+3
    const int k1 = 2 * it + 1, k2 = 2 * it + 2, k3 = 2 * it + 3;
    PHASE(0, 0, 1, stage_half(srcA, 0,  k1, A1h0, t), );
    PHASE(0, 1, 0, stage_half(srcA, H1, k1, A1h1, t), );
    PHASE(0, 2, 0, stage_half(srcB, 0,  k2, B0h0, t), );
    PHASE(0, 3, 0, stage_half(srcB, H1, k2, B0h1, t), VM4);
    PHASE(1, 0, 1, stage_half(srcA, 0,  k2, A0h0, t), );
    PHASE(1, 1, 0, stage_half(srcA, H1, k2, A0h1, t), );
    PHASE(1, 2, 0, stage_half(srcB, 0,  k3, B1h0, t), );
    PHASE(1, 3, 0, stage_half(srcB, H1, k3, B1h1, t), VM4);
  }
  // final iteration: tiles 14 (P0), 15 (P1)
  PHASE(0, 0, 1, stage_half(srcA, 0,  15, A1h0, t), );
  PHASE(0, 1, 0, stage_half(srcA, H1, 15, A1h1, t), );
  PHASE(0, 2, 0, , );
  PHASE(0, 3, 0, , VM0);
  PHASE(1, 0, 1, , );
  PHASE(1, 1, 0, , );
  PHASE(1, 2, 0, , );
  PHASE(1, 3, 0, , );

  // epilogue: row = m0 + wr*128 + fm*16 + (l>>4)*4 + j ; col = c0 + wc*64 + fn*16 + (l&15)
  const int rowb = m0 + wr * 128 + (l >> 4) * 4;
  if (EPI == 0) {
    const int cwb = c0 + wc * 64;
    const int plane = cwb >> 10;            // wave-uniform (0=q,1=k,2=v)
    unsigned short* P = (plane == 0) ? P0 : (plane == 1) ? P1 : P2;
    const int ccb = (cwb & 1023) + (l & 15);
#pragma unroll
    for (int fm = 0; fm < 8; ++fm)
#pragma unroll
      for (int fn = 0; fn < 4; ++fn)
#pragma unroll
        for (int j = 0; j < 4; ++j) {
          int r = rowb + fm * 16 + j;
          int cc = ccb + fn * 16;
          float v = acc[fm][fn][j];
          if (plane < 2) v = (v > 0.f) ? v + 1.f : __expf(v);   // elu + 1
          P[(long)r * 1024 + cc] = f2bf(v);
        }
  } else {
    const int cb = c0 + wc * 64 + (l & 15);
#pragma unroll
    for (int fm = 0; fm < 8; ++fm)
#pragma unroll
      for (int fn = 0; fn < 4; ++fn) {
        float bs = bias[cb + fn * 16];
#pragma unroll
        for (int j = 0; j < 4; ++j) {
          int r = rowb + fm * 16 + j;
          Cf[(long)r * 1024 + cb + fn * 16] = acc[fm][fn][j] + bs;
        }
      }
  }
}

// ---------------- attention pass 1: kv[b,h,d,e], ksum[b,h,d] -------------------
__global__ __launch_bounds__(256) void attn_kv(const unsigned short* __restrict__ kp,
                                               const unsigned short* __restrict__ vp,
                                               float* __restrict__ kvg,
                                               float* __restrict__ ksumg, int b0) {
  const int h = blockIdx.y;
  const int b = b0 + ((blockIdx.x * 256) >> 12);
  const int t = threadIdx.x;
  const int d0 = (t >> 4) * 4;
  const int e0 = (t & 15) * 4;
  __shared__ float kt[32][64];
  __shared__ float vt[32][64];
  float kvloc[4][4] = {};
  float ksumloc = 0.f;
  const int rowbase = blockIdx.x * 256;     // chunk-local
  for (int s = 0; s < 8; ++s) {
    __syncthreads();
#pragma unroll
    for (int i = 0; i < 2; ++i) {
      int idx = i * 256 + t;
      int r = idx >> 4, c4 = (idx & 15) * 4;
      long o = (long)(rowbase + s * 32 + r) * 1024 + h * 64 + c4;
      ushort4 kk = *(const ushort4*)&kp[o];
      ushort4 vv = *(const ushort4*)&vp[o];
      *(float4*)&kt[r][c4] = make_float4(bf2f(kk.x), bf2f(kk.y), bf2f(kk.z), bf2f(kk.w));
      *(float4*)&vt[r][c4] = make_float4(bf2f(vv.x), bf2f(vv.y), bf2f(vv.z), bf2f(vv.w));
    }
    __syncthreads();
    for (int nn = 0; nn < 32; ++nn) {
      const float4 kf = *(const float4*)&kt[nn][d0];
      const float4 vf = *(const float4*)&vt[nn][e0];
      float ka[4] = {kf.x, kf.y, kf.z, kf.w};
      float va[4] = {vf.x, vf.y, vf.z, vf.w};
#pragma unroll
      for (int i = 0; i < 4; ++i)
#pragma unroll
        for (int j = 0; j < 4; ++j) kvloc[i][j] += ka[i] * va[j];
      if (t < 64) ksumloc += kt[nn][t];
    }
  }
  float* kvdst = kvg + (b * HEADS + h) * 4096;
#pragma unroll
  for (int i = 0; i < 4; ++i)
#pragma unroll
    for (int j = 0; j < 4; ++j)
      atomicAdd(&kvdst[(d0 + i) * 64 + e0 + j], kvloc[i][j]);
  if (t < 64) atomicAdd(&ksumg[(b * HEADS + h) * 64 + t], ksumloc);
}

// ---------------- attention pass 2: out = (q@kv)/(q.ksum+1e-6), 1 barrier ------
__global__ __launch_bounds__(256) void attn_out(const unsigned short* __restrict__ qp,
                                                const float* __restrict__ kvg,
                                                const float* __restrict__ ksumg,
                                                unsigned short* __restrict__ Aout, int b0) {
  const int nc = blockIdx.x;                // 64-row group (chunk-local)
  const int h = blockIdx.y;
  const int b = b0 + ((nc * 64) >> 12);
  const int t = threadIdx.x;
  __shared__ float kvs[4096];
  __shared__ float qs[64][64];
  __shared__ float ks_s[64];
  const float* src = kvg + (b * HEADS + h) * 4096;
#pragma unroll
  for (int i = 0; i < 4; ++i)
    ((float4*)kvs)[i * 256 + t] = ((const float4*)src)[i * 256 + t];
  if (t < 64) ks_s[t] = ksumg[(b * HEADS + h) * 64 + t];
  {
    int r = t >> 2, cg = (t & 3) * 16;
    const unsigned short* qrow = qp + (long)(nc * 64 + r) * 1024 + h * 64 + cg;
    bf16x8 v0 = *(const bf16x8*)qrow;
    bf16x8 v1 = *(const bf16x8*)(qrow + 8);
#pragma unroll
    for (int j = 0; j < 8; ++j) {
      qs[r][cg + j]     = bf2f((unsigned short)v0[j]);
      qs[r][cg + 8 + j] = bf2f((unsigned short)v1[j]);
    }
  }
  __syncthreads();
  const int e = t & 63, wv = t >> 6;
#pragma unroll 4
  for (int rr = 0; rr < 16; ++rr) {
    int r = wv * 16 + rr;
    float num = 0.f, den = 0.f;
#pragma unroll
    for (int d = 0; d < 64; ++d) {
      float qd = qs[r][d];
      num = fmaf(qd, kvs[d * 64 + e], num);
      den = fmaf(qd, ks_s[d], den);
    }
    float o = num / (den + 1e-6f);
    Aout[(long)(nc * 64 + r) * 1024 + h * 64 + e] = f2bf(o);
  }
}

// ---------------- launch ----------------

extern "C" void kernel_launch(void* const* d_in, const int* in_sizes, int n_in,
                              void* d_out, int out_size, void* d_ws, size_t ws_size,
                              hipStream_t stream) {
  const float* x     = (const float*)d_in[0];
  const float* Wqkv  = (const float*)d_in[1];
  const float* Wproj = (const float*)d_in[2];
  const float* bproj = (const float*)d_in[3];

  const size_t SZ_BT1  = 3072UL * 1024 * 2;
  const size_t SZ_BT2  = 1024UL * 1024 * 2;
  const size_t SZ_KV   = 4UL * HEADS * 64 * 64 * 4;   // 1 MB (all batches)
  const size_t SZ_KSUM = 4UL * HEADS * 64 * 4;
  const size_t BASE    = SZ_BT1 + SZ_BT2 + SZ_KV + SZ_KSUM;   // 9,453,568

  // chunk = 16384/NB rows; per-chunk ws: Ax,Kp,Vp planes (Q -> d_out region)
  int NB;
  if      (ws_size >= BASE + 3UL * 16384 * 2048) NB = 1;
  else if (ws_size >= BASE + 3UL * 8192 * 2048)  NB = 2;
  else if (ws_size >= BASE + 3UL * 4096 * 2048)  NB = 4;
  else return;
  const int MCH = 16384 / NB;

  size_t off = 0;
  char* ws = (char*)d_ws;
  unsigned short* Bt1 = (unsigned short*)(ws + off); off += SZ_BT1;
  unsigned short* Bt2 = (unsigned short*)(ws + off); off += SZ_BT2;
  float*          kvg = (float*)(ws + off);          off += SZ_KV;
  float*          ksm = (float*)(ws + off);          off += SZ_KSUM;
  unsigned short* Ax  = (unsigned short*)(ws + off); off += (size_t)MCH * 2048;
  unsigned short* Kp  = (unsigned short*)(ws + off); off += (size_t)MCH * 2048;
  unsigned short* Vp  = (unsigned short*)(ws + off);

  hipMemsetAsync(kvg, 0, SZ_KV + SZ_KSUM, stream);

  conv_w<<<dim3(16, 48), 256, 0, stream>>>(Wqkv, Bt1, 3072);
  conv_w<<<dim3(16, 16), 256, 0, stream>>>(Wproj, Bt2, 1024);

  for (int c = 0; c < NB; ++c) {
    const long row0 = (long)c * MCH;
    const float* xc = x + row0 * 1024;
    float* outc = (float*)d_out + row0 * 1024;
    unsigned short* Qp = (unsigned short*)outc;   // dead region until gemm2(c)
    const int b0 = (int)(row0 / 4096);

    conv_x<<<dim3(MCH), 256, 0, stream>>>(xc, Ax);
    gemm8<0><<<dim3(12, MCH / 256), 512, 0, stream>>>(Ax, Bt1, Qp, Kp, Vp,
                                                      nullptr, nullptr);
    attn_kv<<<dim3(MCH / 256, HEADS), 256, 0, stream>>>(Kp, Vp, kvg, ksm, b0);
    attn_out<<<dim3(MCH / 64, HEADS), 256, 0, stream>>>(Qp, kvg, ksm, Ax, b0);
    gemm8<1><<<dim3(4, MCH / 256), 512, 0, stream>>>(Ax, Bt2, nullptr, nullptr, nullptr,
                                                     outc, bproj);
  }
}

// Round 5
// 416.515 us; speedup vs baseline: 1.9006x; 1.4217x over previous
//
#include <hip/hip_runtime.h>
#include <hip/hip_bf16.h>

// LinAtten: x[4,4096,1024] -> qkv GEMM -> elu+1 -> linear attention -> proj GEMM.
// bf16 MFMA GEMMs on the 256^2 8-phase schedule. Attention tail reassociated:
//   out = (z .* q) @ KW_b + bias,  KW_b = blockdiag(kv_b) @ Wproj  (537 MFLOP)
// which deletes the LDS-bound attn_out kernel (217us in r4).

#define DIM    1024
#define HEADS  16
#define SEQ    4096

typedef __attribute__((ext_vector_type(8))) short bf16x8;
typedef __attribute__((ext_vector_type(4))) float f32x4;

__device__ __forceinline__ unsigned short f2bf(float f) {
  unsigned u = __float_as_uint(f);
  u += 0x7fffu + ((u >> 16) & 1u);          // RNE
  return (unsigned short)(u >> 16);
}
__device__ __forceinline__ float bf2f(unsigned short h) {
  return __uint_as_float((unsigned)h << 16);
}
__device__ __forceinline__ void gload_lds16(const void* g, void* l) {
  __builtin_amdgcn_global_load_lds((const __attribute__((address_space(1))) void*)g,
                                   (__attribute__((address_space(3))) void*)l, 16, 0, 0);
}

// ---------------- conversions ----------------

__global__ __launch_bounds__(256) void conv_x(const float* __restrict__ x,
                                              unsigned short* __restrict__ Ax) {
  int idx = blockIdx.x * 256 + threadIdx.x;       // float4 index
  float4 v = ((const float4*)x)[idx];
  ushort4 h;
  h.x = f2bf(v.x); h.y = f2bf(v.y); h.z = f2bf(v.z); h.w = f2bf(v.w);
  ((ushort4*)Ax)[idx] = h;
}

// W [1024, Ncols] f32 -> Bt [Ncols][1024] bf16 (transpose via LDS tile)
__global__ __launch_bounds__(256) void conv_w(const float* __restrict__ W,
                                              unsigned short* __restrict__ Bt,
                                              int Ncols) {
  __shared__ float tile[64][65];
  const int kk0 = blockIdx.x * 64;
  const int c0  = blockIdx.y * 64;
  const int t = threadIdx.x;
  const int cl = t & 63, kl = t >> 6;
#pragma unroll
  for (int i = 0; i < 16; ++i)
    tile[kl + i * 4][cl] = W[(long)(kk0 + kl + i * 4) * Ncols + c0 + cl];
  __syncthreads();
#pragma unroll
  for (int i = 0; i < 16; ++i) {
    int c = kl + i * 4;
    Bt[(long)(c0 + c) * 1024 + kk0 + cl] = f2bf(tile[cl][c]);
  }
}

// ---------------- 256^2 8-phase bf16 GEMM --------------------------------------

__device__ __forceinline__ void stage_half(const unsigned short* srcBase, long rowOff,
                                           int kt, unsigned short* ldsBase, int t) {
  const unsigned short* s0 = srcBase + rowOff + (long)kt * 64;
  gload_lds16(s0, ldsBase + t * 8);                      // rows H*128 + 0..63
  gload_lds16(s0 + 64 * 1024, ldsBase + 4096 + t * 8);   // rows H*128 + 64..127
}

#define MF(a, b, c) __builtin_amdgcn_mfma_f32_16x16x32_bf16(a, b, c, 0, 0, 0)

#define PHASE(P, qd, READB, STAGE, WAIT)                                          \
  {                                                                               \
    const unsigned short* ab = &lds[(P) * 32768 + abase + (qd) * 2048];           \
    bf16x8 a00 = *(const bf16x8*)(ab + sl0);                                      \
    bf16x8 a01 = *(const bf16x8*)(ab + sl1);                                      \
    bf16x8 a10 = *(const bf16x8*)(ab + 1024 + sl0);                               \
    bf16x8 a11 = *(const bf16x8*)(ab + 1024 + sl1);                               \
    if (READB) {                                                                  \
      const unsigned short* bb = &lds[(P) * 32768 + 16384 + bbase];               \
      bfr[0][0] = *(const bf16x8*)(bb + sl0);                                     \
      bfr[0][1] = *(const bf16x8*)(bb + sl1);                                     \
      bfr[1][0] = *(const bf16x8*)(bb + 1024 + sl0);                              \
      bfr[1][1] = *(const bf16x8*)(bb + 1024 + sl1);                              \
      bfr[2][0] = *(const bf16x8*)(bb + 2048 + sl0);                              \
      bfr[2][1] = *(const bf16x8*)(bb + 2048 + sl1);                              \
      bfr[3][0] = *(const bf16x8*)(bb + 3072 + sl0);                              \
      bfr[3][1] = *(const bf16x8*)(bb + 3072 + sl1);                              \
    }                                                                             \
    STAGE;                                                                        \
    WAIT;                                                                         \
    asm volatile("s_barrier" ::: "memory");                                       \
    __builtin_amdgcn_s_setprio(1);                                                \
    acc[(qd)*2][0] = MF(a00, bfr[0][0], acc[(qd)*2][0]);                          \
    acc[(qd)*2][1] = MF(a00, bfr[1][0], acc[(qd)*2][1]);                          \
    acc[(qd)*2][2] = MF(a00, bfr[2][0], acc[(qd)*2][2]);                          \
    acc[(qd)*2][3] = MF(a00, bfr[3][0], acc[(qd)*2][3]);                          \
    acc[(qd)*2][0] = MF(a01, bfr[0][1], acc[(qd)*2][0]);                          \
    acc[(qd)*2][1] = MF(a01, bfr[1][1], acc[(qd)*2][1]);                          \
    acc[(qd)*2][2] = MF(a01, bfr[2][1], acc[(qd)*2][2]);                          \
    acc[(qd)*2][3] = MF(a01, bfr[3][1], acc[(qd)*2][3]);                          \
    acc[(qd)*2+1][0] = MF(a10, bfr[0][0], acc[(qd)*2+1][0]);                      \
    acc[(qd)*2+1][1] = MF(a10, bfr[1][0], acc[(qd)*2+1][1]);                      \
    acc[(qd)*2+1][2] = MF(a10, bfr[2][0], acc[(qd)*2+1][2]);                      \
    acc[(qd)*2+1][3] = MF(a10, bfr[3][0], acc[(qd)*2+1][3]);                      \
    acc[(qd)*2+1][0] = MF(a11, bfr[0][1], acc[(qd)*2+1][0]);                      \
    acc[(qd)*2+1][1] = MF(a11, bfr[1][1], acc[(qd)*2+1][1]);                      \
    acc[(qd)*2+1][2] = MF(a11, bfr[2][1], acc[(qd)*2+1][2]);                      \
    acc[(qd)*2+1][3] = MF(a11, bfr[3][1], acc[(qd)*2+1][3]);                      \
    __builtin_amdgcn_s_setprio(0);                                                \
    asm volatile("s_barrier" ::: "memory");                                       \
  }

#define VM4 asm volatile("s_waitcnt vmcnt(4)" ::: "memory")
#define VM0 asm volatile("s_waitcnt vmcnt(0)" ::: "memory")

// EPI 0: write q/k/v planes (elu+1 on q,k), bf16.  EPI 1: +bias, f32, per-batch B
// (bstride elements between consecutive 4096-row batches' B matrices).
template <int EPI>
__global__ __launch_bounds__(512) void gemm8(const unsigned short* __restrict__ A,
                                             const unsigned short* __restrict__ Bt,
                                             unsigned short* __restrict__ P0,
                                             unsigned short* __restrict__ P1,
                                             unsigned short* __restrict__ P2,
                                             float* __restrict__ Cf,
                                             const float* __restrict__ bias,
                                             long bstride) {
  __shared__ unsigned short lds[65536];     // 128 KiB
  const int t = threadIdx.x;
  const int l = t & 63, w = t >> 6;
  const int wr = w >> 2, wc = w & 3;        // 2x4 wave grid
  const int m0 = blockIdx.y * 256;
  const int c0 = blockIdx.x * 256;

  f32x4 acc[8][4] = {};
  bf16x8 bfr[4][2];

  const int sl0 = (((l >> 4)) ^ (l & 7)) * 8;
  const int sl1 = ((4 + (l >> 4)) ^ (l & 7)) * 8;
  const int abase = wr * 8192 + (l & 15) * 64;
  const int bbase = (wc >> 1) * 8192 + (wc & 1) * 4096 + (l & 15) * 64;

  const int sw = ((t & 7) ^ ((t >> 3) & 7)) * 8;
  const unsigned short* srcA = A + (long)(m0 + (t >> 3)) * 1024 + sw;
  const unsigned short* srcB = Bt + (long)(m0 >> 12) * bstride +
                               (long)(c0 + (t >> 3)) * 1024 + sw;
  const long H1 = 128L * 1024;

  unsigned short* A0h0 = &lds[0];      unsigned short* A0h1 = &lds[8192];
  unsigned short* B0h0 = &lds[16384];  unsigned short* B0h1 = &lds[24576];
  unsigned short* A1h0 = &lds[32768];  unsigned short* A1h1 = &lds[40960];
  unsigned short* B1h0 = &lds[49152];  unsigned short* B1h1 = &lds[57344];

  stage_half(srcA, 0,  0, A0h0, t);  stage_half(srcA, H1, 0, A0h1, t);
  stage_half(srcB, 0,  0, B0h0, t);  stage_half(srcB, H1, 0, B0h1, t);
  stage_half(srcB, 0,  1, B1h0, t);  stage_half(srcB, H1, 1, B1h1, t);
  VM4;
  asm volatile("s_barrier" ::: "memory");

  for (int it = 0; it < 7; ++it) {
    const int k1 = 2 * it + 1, k2 = 2 * it + 2, k3 = 2 * it + 3;
    PHASE(0, 0, 1, stage_half(srcA, 0,  k1, A1h0, t), );
    PHASE(0, 1, 0, stage_half(srcA, H1, k1, A1h1, t), );
    PHASE(0, 2, 0, stage_half(srcB, 0,  k2, B0h0, t), );
    PHASE(0, 3, 0, stage_half(srcB, H1, k2, B0h1, t), VM4);
    PHASE(1, 0, 1, stage_half(srcA, 0,  k2, A0h0, t), );
    PHASE(1, 1, 0, stage_half(srcA, H1, k2, A0h1, t), );
    PHASE(1, 2, 0, stage_half(srcB, 0,  k3, B1h0, t), );
    PHASE(1, 3, 0, stage_half(srcB, H1, k3, B1h1, t), VM4);
  }
  PHASE(0, 0, 1, stage_half(srcA, 0,  15, A1h0, t), );
  PHASE(0, 1, 0, stage_half(srcA, H1, 15, A1h1, t), );
  PHASE(0, 2, 0, , );
  PHASE(0, 3, 0, , VM0);
  PHASE(1, 0, 1, , );
  PHASE(1, 1, 0, , );
  PHASE(1, 2, 0, , );
  PHASE(1, 3, 0, , );

  const int rowb = m0 + wr * 128 + (l >> 4) * 4;
  if (EPI == 0) {
    const int cwb = c0 + wc * 64;
    const int plane = cwb >> 10;            // wave-uniform (0=q,1=k,2=v)
    unsigned short* P = (plane == 0) ? P0 : (plane == 1) ? P1 : P2;
    const int ccb = (cwb & 1023) + (l & 15);
#pragma unroll
    for (int fm = 0; fm < 8; ++fm)
#pragma unroll
      for (int fn = 0; fn < 4; ++fn)
#pragma unroll
        for (int j = 0; j < 4; ++j) {
          int r = rowb + fm * 16 + j;
          int cc = ccb + fn * 16;
          float v = acc[fm][fn][j];
          if (plane < 2) v = (v > 0.f) ? v + 1.f : __expf(v);   // elu + 1
          P[(long)r * 1024 + cc] = f2bf(v);
        }
  } else {
    const int cb = c0 + wc * 64 + (l & 15);
#pragma unroll
    for (int fm = 0; fm < 8; ++fm)
#pragma unroll
      for (int fn = 0; fn < 4; ++fn) {
        float bs = bias[cb + fn * 16];
#pragma unroll
        for (int j = 0; j < 4; ++j) {
          int r = rowb + fm * 16 + j;
          Cf[(long)r * 1024 + cb + fn * 16] = acc[fm][fn][j] + bs;
        }
      }
  }
}

// ---------------- attention pass 1: kv[b,h,d,e], ksum[b,h,d] -------------------
__global__ __launch_bounds__(256) void attn_kv(const unsigned short* __restrict__ kp,
                                               const unsigned short* __restrict__ vp,
                                               float* __restrict__ kvg,
                                               float* __restrict__ ksumg, int b0) {
  const int h = blockIdx.y;
  const int b = b0 + ((blockIdx.x * 256) >> 12);
  const int t = threadIdx.x;
  const int d0 = (t >> 4) * 4;
  const int e0 = (t & 15) * 4;
  __shared__ float kt[32][64];
  __shared__ float vt[32][64];
  float kvloc[4][4] = {};
  float ksumloc = 0.f;
  const int rowbase = blockIdx.x * 256;     // chunk-local
  for (int s = 0; s < 8; ++s) {
    __syncthreads();
#pragma unroll
    for (int i = 0; i < 2; ++i) {
      int idx = i * 256 + t;
      int r = idx >> 4, c4 = (idx & 15) * 4;
      long o = (long)(rowbase + s * 32 + r) * 1024 + h * 64 + c4;
      ushort4 kk = *(const ushort4*)&kp[o];
      ushort4 vv = *(const ushort4*)&vp[o];
      *(float4*)&kt[r][c4] = make_float4(bf2f(kk.x), bf2f(kk.y), bf2f(kk.z), bf2f(kk.w));
      *(float4*)&vt[r][c4] = make_float4(bf2f(vv.x), bf2f(vv.y), bf2f(vv.z), bf2f(vv.w));
    }
    __syncthreads();
    for (int nn = 0; nn < 32; ++nn) {
      const float4 kf = *(const float4*)&kt[nn][d0];
      const float4 vf = *(const float4*)&vt[nn][e0];
      float ka[4] = {kf.x, kf.y, kf.z, kf.w};
      float va[4] = {vf.x, vf.y, vf.z, vf.w};
#pragma unroll
      for (int i = 0; i < 4; ++i)
#pragma unroll
        for (int j = 0; j < 4; ++j) kvloc[i][j] += ka[i] * va[j];
      if (t < 64) ksumloc += kt[nn][t];
    }
  }
  float* kvdst = kvg + (b * HEADS + h) * 4096;
#pragma unroll
  for (int i = 0; i < 4; ++i)
#pragma unroll
    for (int j = 0; j < 4; ++j)
      atomicAdd(&kvdst[(d0 + i) * 64 + e0 + j], kvloc[i][j]);
  if (t < 64) atomicAdd(&ksumg[(b * HEADS + h) * 64 + t], ksumloc);
}

// ---------------- qz_scale: Aq[n][c] = q[n][c] / (q[n,h,:].ksum[b,h,:] + 1e-6) --
// 4 rows/block (1 per wave); lane l holds q cols l*16..l*16+15 (head h=l>>2).
__global__ __launch_bounds__(256) void qz_scale(const unsigned short* __restrict__ Qp,
                                                const float* __restrict__ ksumg,
                                                unsigned short* __restrict__ Aq,
                                                int b0) {
  __shared__ float ks_lds[1024];
  const int t = threadIdx.x, l = t & 63, w = t >> 6;
  const int blk = blockIdx.x;
  const int b = b0 + (blk >> 10);           // 1024 blocks per batch
  ((float4*)ks_lds)[t] = ((const float4*)(ksumg + (long)b * 1024))[t];
  __syncthreads();
  const long base = (long)(blk * 4 + w) * 1024 + l * 16;
  bf16x8 v0 = *(const bf16x8*)&Qp[base];
  bf16x8 v1 = *(const bf16x8*)&Qp[base + 8];
  float qf[16];
#pragma unroll
  for (int j = 0; j < 8; ++j) {
    qf[j]     = bf2f((unsigned short)v0[j]);
    qf[8 + j] = bf2f((unsigned short)v1[j]);
  }
  const float* ks = &ks_lds[(l >> 2) * 64 + (l & 3) * 16];
  float den = 0.f;
#pragma unroll
  for (int j = 0; j < 16; ++j) den = fmaf(qf[j], ks[j], den);
  den += __shfl_xor(den, 1);
  den += __shfl_xor(den, 2);
  const float z = 1.f / (den + 1e-6f);
#pragma unroll
  for (int j = 0; j < 8; ++j) {
    v0[j] = (short)f2bf(qf[j] * z);
    v1[j] = (short)f2bf(qf[8 + j] * z);
  }
  *(bf16x8*)&Aq[base] = v0;
  *(bf16x8*)&Aq[base + 8] = v1;
}

// ---------------- kvw: KWt[b][c][h*64+d] = sum_e kv[b,h,d,e] * Wproj[h*64+e][c] --
// Per block (ctile, h, batch): out [256 c x 64 d], K=64. MFMA from L2 (no LDS).
// A-operand rows = c from Bt2[c][h*64+e]; B-operand "Bt rows" = d from kv[d][e].
__global__ __launch_bounds__(256) void kvw(const float* __restrict__ kvg,
                                           const unsigned short* __restrict__ Bt2,
                                           unsigned short* __restrict__ KWt,
                                           int b0) {
  const int mt = blockIdx.x;                // c-tile (256 rows)
  const int h  = blockIdx.y;
  const int b  = b0 + blockIdx.z;
  const int t = threadIdx.x, l = t & 63, w = t >> 6;
  const int cb = mt * 256 + w * 64;
  f32x4 acc[4][4] = {};
  const float* kvh = kvg + (long)(b * HEADS + h) * 4096;
#pragma unroll
  for (int ks = 0; ks < 2; ++ks) {
    const int e0 = ks * 32 + (l >> 4) * 8;
    bf16x8 afr[4], bfq[4];
#pragma unroll
    for (int mi = 0; mi < 4; ++mi) {
      int c = cb + mi * 16 + (l & 15);
      afr[mi] = *(const bf16x8*)&Bt2[(long)c * 1024 + h * 64 + e0];
    }
#pragma unroll
    for (int ni = 0; ni < 4; ++ni) {
      int d = ni * 16 + (l & 15);
      const float* kp = &kvh[d * 64 + e0];
      bf16x8 bv;
#pragma unroll
      for (int j = 0; j < 8; ++j) bv[j] = (short)f2bf(kp[j]);
      bfq[ni] = bv;
    }
#pragma unroll
    for (int mi = 0; mi < 4; ++mi)
#pragma unroll
      for (int ni = 0; ni < 4; ++ni)
        acc[mi][ni] = MF(afr[mi], bfq[ni], acc[mi][ni]);
  }
  unsigned short* dst = KWt + (long)b * 1048576;
#pragma unroll
  for (int mi = 0; mi < 4; ++mi)
#pragma unroll
    for (int ni = 0; ni < 4; ++ni)
#pragma unroll
      for (int j = 0; j < 4; ++j) {
        int c = cb + mi * 16 + (l >> 4) * 4 + j;
        int d = ni * 16 + (l & 15);
        dst[(long)c * 1024 + h * 64 + d] = f2bf(acc[mi][ni][j]);
      }
}

// ---------------- launch ----------------

extern "C" void kernel_launch(void* const* d_in, const int* in_sizes, int n_in,
                              void* d_out, int out_size, void* d_ws, size_t ws_size,
                              hipStream_t stream) {
  const float* x     = (const float*)d_in[0];
  const float* Wqkv  = (const float*)d_in[1];
  const float* Wproj = (const float*)d_in[2];
  const float* bproj = (const float*)d_in[3];

  const size_t SZ_KV   = 4UL * HEADS * 64 * 64 * 4;   // 1,048,576
  const size_t SZ_KSUM = 4UL * HEADS * 64 * 4;        //    16,384
  const size_t SZ_BT2  = 1024UL * 1024 * 2;           // 2,097,152
  const size_t SZ_BT1  = 3072UL * 1024 * 2;           // 6,291,456
  const size_t SZ_KWT  = 4UL * 1024 * 1024 * 2;       // 8,388,608
  const size_t HEAD_SZ = SZ_KV + SZ_KSUM + SZ_BT2;    // 3,162,112

  // NB=1: KWt aliases dead Bt1+Vp head (layout kv,ksum,Bt2,Ax,Kp,Bt1,Vp).
  int NB;
  if      (ws_size >= HEAD_SZ + 3UL * 16384 * 2048 + SZ_BT1)            NB = 1;
  else if (ws_size >= HEAD_SZ + 3UL * 8192 * 2048 + SZ_BT1 + SZ_KWT)    NB = 2;
  else if (ws_size >= HEAD_SZ + 3UL * 4096 * 2048 + SZ_BT1 + SZ_KWT)    NB = 4;
  else return;
  const int MCH = 16384 / NB;
  const size_t SZ_PLANE = (size_t)MCH * 2048;

  size_t off = 0;
  char* ws = (char*)d_ws;
  float*          kvg = (float*)(ws + off);          off += SZ_KV;
  float*          ksm = (float*)(ws + off);          off += SZ_KSUM;
  unsigned short* Bt2 = (unsigned short*)(ws + off); off += SZ_BT2;
  unsigned short* Ax  = (unsigned short*)(ws + off); off += SZ_PLANE;
  unsigned short* Kp  = (unsigned short*)(ws + off); off += SZ_PLANE;
  unsigned short* Bt1 = (unsigned short*)(ws + off); off += SZ_BT1;
  unsigned short* Vp  = (unsigned short*)(ws + off); off += SZ_PLANE;
  unsigned short* KWt = (NB == 1) ? Bt1               // Bt1+Vp dead by kvw time
                                  : (unsigned short*)(ws + off);

  hipMemsetAsync(kvg, 0, SZ_KV + SZ_KSUM, stream);

  conv_w<<<dim3(16, 48), 256, 0, stream>>>(Wqkv, Bt1, 3072);
  conv_w<<<dim3(16, 16), 256, 0, stream>>>(Wproj, Bt2, 1024);

  for (int c = 0; c < NB; ++c) {
    const long row0 = (long)c * MCH;
    const float* xc = x + row0 * 1024;
    float* outc = (float*)d_out + row0 * 1024;
    unsigned short* Qp = (unsigned short*)outc;   // dead region until gemm2(c)
    const int b0 = (int)(row0 / 4096);

    conv_x<<<dim3(MCH), 256, 0, stream>>>(xc, Ax);
    gemm8<0><<<dim3(12, MCH / 256), 512, 0, stream>>>(Ax, Bt1, Qp, Kp, Vp,
                                                      nullptr, nullptr, 0L);
    attn_kv<<<dim3(MCH / 256, HEADS), 256, 0, stream>>>(Kp, Vp, kvg, ksm, b0);
    qz_scale<<<dim3(MCH / 4), 256, 0, stream>>>(Qp, ksm, Ax, b0);
    kvw<<<dim3(4, HEADS, MCH / 4096), 256, 0, stream>>>(kvg, Bt2, KWt, b0);
    gemm8<1><<<dim3(4, MCH / 256), 512, 0, stream>>>(
        Ax, KWt + (long)b0 * 1048576, nullptr, nullptr, nullptr,
        outc, bproj, 1048576L);
  }
}

// Round 6
// 328.345 us; speedup vs baseline: 2.4110x; 1.2685x over previous
//
#include <hip/hip_runtime.h>
#include <hip/hip_bf16.h>

// LinAtten: x[4,4096,1024] -> qkv GEMM -> elu+1 -> linear attention -> proj GEMM.
// bf16 MFMA GEMMs on the 256^2 8-phase schedule. Attention tail reassociated:
//   out = (z .* q) @ KW_b + bias,  KW_b = blockdiag(kv_b) @ Wproj
// K,V planes are written TRANSPOSED [bl][h][d][n] by gemm8<0>'s epilogue so
// attn_kv is a pure MFMA GEMM with direct global fragment loads (no LDS).

#define DIM    1024
#define HEADS  16
#define SEQ    4096

typedef __attribute__((ext_vector_type(8))) short bf16x8;
typedef __attribute__((ext_vector_type(4))) float f32x4;

__device__ __forceinline__ unsigned short f2bf(float f) {
  unsigned u = __float_as_uint(f);
  u += 0x7fffu + ((u >> 16) & 1u);          // RNE
  return (unsigned short)(u >> 16);
}
__device__ __forceinline__ float bf2f(unsigned short h) {
  return __uint_as_float((unsigned)h << 16);
}
__device__ __forceinline__ void gload_lds16(const void* g, void* l) {
  __builtin_amdgcn_global_load_lds((const __attribute__((address_space(1))) void*)g,
                                   (__attribute__((address_space(3))) void*)l, 16, 0, 0);
}

// ---------------- conversions ----------------

__global__ __launch_bounds__(256) void conv_x(const float* __restrict__ x,
                                              unsigned short* __restrict__ Ax) {
  int idx = blockIdx.x * 256 + threadIdx.x;       // float4 index
  float4 v = ((const float4*)x)[idx];
  ushort4 h;
  h.x = f2bf(v.x); h.y = f2bf(v.y); h.z = f2bf(v.z); h.w = f2bf(v.w);
  ((ushort4*)Ax)[idx] = h;
}

// W [1024, Ncols] f32 -> Bt [Ncols][1024] bf16 (transpose via LDS tile)
__global__ __launch_bounds__(256) void conv_w(const float* __restrict__ W,
                                              unsigned short* __restrict__ Bt,
                                              int Ncols) {
  __shared__ float tile[64][65];
  const int kk0 = blockIdx.x * 64;
  const int c0  = blockIdx.y * 64;
  const int t = threadIdx.x;
  const int cl = t & 63, kl = t >> 6;
#pragma unroll
  for (int i = 0; i < 16; ++i)
    tile[kl + i * 4][cl] = W[(long)(kk0 + kl + i * 4) * Ncols + c0 + cl];
  __syncthreads();
#pragma unroll
  for (int i = 0; i < 16; ++i) {
    int c = kl + i * 4;
    Bt[(long)(c0 + c) * 1024 + kk0 + cl] = f2bf(tile[cl][c]);
  }
}

// ---------------- 256^2 8-phase bf16 GEMM --------------------------------------

__device__ __forceinline__ void stage_half(const unsigned short* srcBase, long rowOff,
                                           int kt, unsigned short* ldsBase, int t) {
  const unsigned short* s0 = srcBase + rowOff + (long)kt * 64;
  gload_lds16(s0, ldsBase + t * 8);                      // rows H*128 + 0..63
  gload_lds16(s0 + 64 * 1024, ldsBase + 4096 + t * 8);   // rows H*128 + 64..127
}

#define MF(a, b, c) __builtin_amdgcn_mfma_f32_16x16x32_bf16(a, b, c, 0, 0, 0)

#define PHASE(P, qd, READB, STAGE, WAIT)                                          \
  {                                                                               \
    const unsigned short* ab = &lds[(P) * 32768 + abase + (qd) * 2048];           \
    bf16x8 a00 = *(const bf16x8*)(ab + sl0);                                      \
    bf16x8 a01 = *(const bf16x8*)(ab + sl1);                                      \
    bf16x8 a10 = *(const bf16x8*)(ab + 1024 + sl0);                               \
    bf16x8 a11 = *(const bf16x8*)(ab + 1024 + sl1);                               \
    if (READB) {                                                                  \
      const unsigned short* bb = &lds[(P) * 32768 + 16384 + bbase];               \
      bfr[0][0] = *(const bf16x8*)(bb + sl0);                                     \
      bfr[0][1] = *(const bf16x8*)(bb + sl1);                                     \
      bfr[1][0] = *(const bf16x8*)(bb + 1024 + sl0);                              \
      bfr[1][1] = *(const bf16x8*)(bb + 1024 + sl1);                              \
      bfr[2][0] = *(const bf16x8*)(bb + 2048 + sl0);                              \
      bfr[2][1] = *(const bf16x8*)(bb + 2048 + sl1);                              \
      bfr[3][0] = *(const bf16x8*)(bb + 3072 + sl0);                              \
      bfr[3][1] = *(const bf16x8*)(bb + 3072 + sl1);                              \
    }                                                                             \
    STAGE;                                                                        \
    WAIT;                                                                         \
    asm volatile("s_barrier" ::: "memory");                                       \
    __builtin_amdgcn_s_setprio(1);                                                \
    acc[(qd)*2][0] = MF(a00, bfr[0][0], acc[(qd)*2][0]);                          \
    acc[(qd)*2][1] = MF(a00, bfr[1][0], acc[(qd)*2][1]);                          \
    acc[(qd)*2][2] = MF(a00, bfr[2][0], acc[(qd)*2][2]);                          \
    acc[(qd)*2][3] = MF(a00, bfr[3][0], acc[(qd)*2][3]);                          \
    acc[(qd)*2][0] = MF(a01, bfr[0][1], acc[(qd)*2][0]);                          \
    acc[(qd)*2][1] = MF(a01, bfr[1][1], acc[(qd)*2][1]);                          \
    acc[(qd)*2][2] = MF(a01, bfr[2][1], acc[(qd)*2][2]);                          \
    acc[(qd)*2][3] = MF(a01, bfr[3][1], acc[(qd)*2][3]);                          \
    acc[(qd)*2+1][0] = MF(a10, bfr[0][0], acc[(qd)*2+1][0]);                      \
    acc[(qd)*2+1][1] = MF(a10, bfr[1][0], acc[(qd)*2+1][1]);                      \
    acc[(qd)*2+1][2] = MF(a10, bfr[2][0], acc[(qd)*2+1][2]);                      \
    acc[(qd)*2+1][3] = MF(a10, bfr[3][0], acc[(qd)*2+1][3]);                      \
    acc[(qd)*2+1][0] = MF(a11, bfr[0][1], acc[(qd)*2+1][0]);                      \
    acc[(qd)*2+1][1] = MF(a11, bfr[1][1], acc[(qd)*2+1][1]);                      \
    acc[(qd)*2+1][2] = MF(a11, bfr[2][1], acc[(qd)*2+1][2]);                      \
    acc[(qd)*2+1][3] = MF(a11, bfr[3][1], acc[(qd)*2+1][3]);                      \
    __builtin_amdgcn_s_setprio(0);                                                \
    asm volatile("s_barrier" ::: "memory");                                       \
  }

#define VM4 asm volatile("s_waitcnt vmcnt(4)" ::: "memory")
#define VM0 asm volatile("s_waitcnt vmcnt(0)" ::: "memory")

// EPI 0: q plane row-major [n][1024] (elu+1); k,v planes TRANSPOSED
//        [bl][h][d][4096] (elu+1 on k only).  EPI 1: +bias, f32, per-batch B.
template <int EPI>
__global__ __launch_bounds__(512) void gemm8(const unsigned short* __restrict__ A,
                                             const unsigned short* __restrict__ Bt,
                                             unsigned short* __restrict__ P0,
                                             unsigned short* __restrict__ P1,
                                             unsigned short* __restrict__ P2,
                                             float* __restrict__ Cf,
                                             const float* __restrict__ bias,
                                             long bstride) {
  __shared__ unsigned short lds[65536];     // 128 KiB
  const int t = threadIdx.x;
  const int l = t & 63, w = t >> 6;
  const int wr = w >> 2, wc = w & 3;        // 2x4 wave grid
  const int m0 = blockIdx.y * 256;
  const int c0 = blockIdx.x * 256;

  f32x4 acc[8][4] = {};
  bf16x8 bfr[4][2];

  const int sl0 = (((l >> 4)) ^ (l & 7)) * 8;
  const int sl1 = ((4 + (l >> 4)) ^ (l & 7)) * 8;
  const int abase = wr * 8192 + (l & 15) * 64;
  const int bbase = (wc >> 1) * 8192 + (wc & 1) * 4096 + (l & 15) * 64;

  const int sw = ((t & 7) ^ ((t >> 3) & 7)) * 8;
  const unsigned short* srcA = A + (long)(m0 + (t >> 3)) * 1024 + sw;
  const unsigned short* srcB = Bt + (long)(m0 >> 12) * bstride +
                               (long)(c0 + (t >> 3)) * 1024 + sw;
  const long H1 = 128L * 1024;

  unsigned short* A0h0 = &lds[0];      unsigned short* A0h1 = &lds[8192];
  unsigned short* B0h0 = &lds[16384];  unsigned short* B0h1 = &lds[24576];
  unsigned short* A1h0 = &lds[32768];  unsigned short* A1h1 = &lds[40960];
  unsigned short* B1h0 = &lds[49152];  unsigned short* B1h1 = &lds[57344];

  stage_half(srcA, 0,  0, A0h0, t);  stage_half(srcA, H1, 0, A0h1, t);
  stage_half(srcB, 0,  0, B0h0, t);  stage_half(srcB, H1, 0, B0h1, t);
  stage_half(srcB, 0,  1, B1h0, t);  stage_half(srcB, H1, 1, B1h1, t);
  VM4;
  asm volatile("s_barrier" ::: "memory");

  for (int it = 0; it < 7; ++it) {
    const int k1 = 2 * it + 1, k2 = 2 * it + 2, k3 = 2 * it + 3;
    PHASE(0, 0, 1, stage_half(srcA, 0,  k1, A1h0, t), );
    PHASE(0, 1, 0, stage_half(srcA, H1, k1, A1h1, t), );
    PHASE(0, 2, 0, stage_half(srcB, 0,  k2, B0h0, t), );
    PHASE(0, 3, 0, stage_half(srcB, H1, k2, B0h1, t), VM4);
    PHASE(1, 0, 1, stage_half(srcA, 0,  k2, A0h0, t), );
    PHASE(1, 1, 0, stage_half(srcA, H1, k2, A0h1, t), );
    PHASE(1, 2, 0, stage_half(srcB, 0,  k3, B1h0, t), );
    PHASE(1, 3, 0, stage_half(srcB, H1, k3, B1h1, t), VM4);
  }
  PHASE(0, 0, 1, stage_half(srcA, 0,  15, A1h0, t), );
  PHASE(0, 1, 0, stage_half(srcA, H1, 15, A1h1, t), );
  PHASE(0, 2, 0, , );
  PHASE(0, 3, 0, , VM0);
  PHASE(1, 0, 1, , );
  PHASE(1, 1, 0, , );
  PHASE(1, 2, 0, , );
  PHASE(1, 3, 0, , );

  const int rowb = m0 + wr * 128 + (l >> 4) * 4;
  if (EPI == 0) {
    const int cwb = c0 + wc * 64;
    const int plane = cwb >> 10;            // wave-uniform (0=q,1=k,2=v)
    if (plane == 0) {
      const int ccb = (cwb & 1023) + (l & 15);
#pragma unroll
      for (int fm = 0; fm < 8; ++fm)
#pragma unroll
        for (int fn = 0; fn < 4; ++fn)
#pragma unroll
          for (int j = 0; j < 4; ++j) {
            int r = rowb + fm * 16 + j;
            float v = acc[fm][fn][j];
            v = (v > 0.f) ? v + 1.f : __expf(v);            // elu + 1
            P0[(long)r * 1024 + ccb + fn * 16] = f2bf(v);
          }
    } else {
      unsigned short* P = (plane == 1) ? P1 : P2;
      const int ccb = (cwb & 1023) + (l & 15);
#pragma unroll
      for (int fm = 0; fm < 8; ++fm) {
        const int n0 = rowb + fm * 16;                      // chunk-local row
        const int bl = n0 >> 12, np = n0 & 4095;
#pragma unroll
        for (int fn = 0; fn < 4; ++fn) {
          const int cc = ccb + fn * 16;                     // 0..1023
          const int h = cc >> 6, d = cc & 63;
          ushort4 o;
#pragma unroll
          for (int j = 0; j < 4; ++j) {
            float v = acc[fm][fn][j];
            if (plane == 1) v = (v > 0.f) ? v + 1.f : __expf(v);   // elu + 1 (k)
            ((unsigned short*)&o)[j] = f2bf(v);
          }
          *(ushort4*)&P[((long)(bl * 16 + h) * 64 + d) * 4096 + np] = o;
        }
      }
    }
  } else {
    const int cb = c0 + wc * 64 + (l & 15);
#pragma unroll
    for (int fm = 0; fm < 8; ++fm)
#pragma unroll
      for (int fn = 0; fn < 4; ++fn) {
        float bs = bias[cb + fn * 16];
#pragma unroll
        for (int j = 0; j < 4; ++j) {
          int r = rowb + fm * 16 + j;
          Cf[(long)r * 1024 + cb + fn * 16] = acc[fm][fn][j] + bs;
        }
      }
  }
}

// ---------------- attention pass 1 (MFMA): kv[b,h,d,e], ksum[b,h,d] ------------
// Kt,Vt: [bl][h][64 d][4096 n] bf16. Grid (4*nbatch, HEADS); block = 4 waves,
// wave w covers 256 n. Fragments straight from global (L2/L3-hot).
__global__ __launch_bounds__(256) void attn_kv(const unsigned short* __restrict__ Kt,
                                               const unsigned short* __restrict__ Vt,
                                               float* __restrict__ kvg,
                                               float* __restrict__ ksumg, int b0) {
  const int bl = blockIdx.x >> 2, cx = blockIdx.x & 3;
  const int h = blockIdx.y;
  const int b = b0 + bl;
  const int t = threadIdx.x, l = t & 63, w = t >> 6;
  const long pbase = ((long)(bl * HEADS + h) * 64) * 4096;
  const unsigned short* kb = Kt + pbase;
  const unsigned short* vb = Vt + pbase;

  f32x4 acc[4][4] = {};
  f32x4 ks[4] = {};
  bf16x8 ones;
#pragma unroll
  for (int j = 0; j < 8; ++j) ones[j] = (short)0x3F80;    // bf16 1.0

  const int lr = l & 15;
  for (int s = 0; s < 8; ++s) {
    const int n0 = cx * 1024 + w * 256 + s * 32 + (l >> 4) * 8;
    bf16x8 af[4], bfq[4];
#pragma unroll
    for (int dt = 0; dt < 4; ++dt)
      af[dt] = *(const bf16x8*)&kb[(long)(dt * 16 + lr) * 4096 + n0];
#pragma unroll
    for (int et = 0; et < 4; ++et)
      bfq[et] = *(const bf16x8*)&vb[(long)(et * 16 + lr) * 4096 + n0];
#pragma unroll
    for (int dt = 0; dt < 4; ++dt) {
#pragma unroll
      for (int et = 0; et < 4; ++et)
        acc[dt][et] = MF(af[dt], bfq[et], acc[dt][et]);
      ks[dt] = MF(af[dt], ones, ks[dt]);
    }
  }

  // C layout: row d = dt*16 + (l>>4)*4 + j, col e = et*16 + (l&15)
  float* kvdst = kvg + (long)(b * HEADS + h) * 4096;
#pragma unroll
  for (int dt = 0; dt < 4; ++dt)
#pragma unroll
    for (int et = 0; et < 4; ++et)
#pragma unroll
      for (int j = 0; j < 4; ++j)
        atomicAdd(&kvdst[(dt * 16 + (l >> 4) * 4 + j) * 64 + et * 16 + lr],
                  acc[dt][et][j]);
  if (lr == 0) {
    float* ksdst = ksumg + (long)(b * HEADS + h) * 64;
#pragma unroll
    for (int dt = 0; dt < 4; ++dt)
#pragma unroll
      for (int j = 0; j < 4; ++j)
        atomicAdd(&ksdst[dt * 16 + (l >> 4) * 4 + j], ks[dt][j]);
  }
}

// ---------------- qz_scale: Aq[n][c] = q[n][c] / (q[n,h,:].ksum[b,h,:] + 1e-6) --
__global__ __launch_bounds__(256) void qz_scale(const unsigned short* __restrict__ Qp,
                                                const float* __restrict__ ksumg,
                                                unsigned short* __restrict__ Aq,
                                                int b0) {
  __shared__ float ks_lds[1024];
  const int t = threadIdx.x, l = t & 63, w = t >> 6;
  const int blk = blockIdx.x;
  const int b = b0 + (blk >> 10);           // 1024 blocks per batch
  ((float4*)ks_lds)[t] = ((const float4*)(ksumg + (long)b * 1024))[t];
  __syncthreads();
  const long base = (long)(blk * 4 + w) * 1024 + l * 16;
  bf16x8 v0 = *(const bf16x8*)&Qp[base];
  bf16x8 v1 = *(const bf16x8*)&Qp[base + 8];
  float qf[16];
#pragma unroll
  for (int j = 0; j < 8; ++j) {
    qf[j]     = bf2f((unsigned short)v0[j]);
    qf[8 + j] = bf2f((unsigned short)v1[j]);
  }
  const float* ks = &ks_lds[(l >> 2) * 64 + (l & 3) * 16];
  float den = 0.f;
#pragma unroll
  for (int j = 0; j < 16; ++j) den = fmaf(qf[j], ks[j], den);
  den += __shfl_xor(den, 1);
  den += __shfl_xor(den, 2);
  const float z = 1.f / (den + 1e-6f);
#pragma unroll
  for (int j = 0; j < 8; ++j) {
    v0[j] = (short)f2bf(qf[j] * z);
    v1[j] = (short)f2bf(qf[8 + j] * z);
  }
  *(bf16x8*)&Aq[base] = v0;
  *(bf16x8*)&Aq[base + 8] = v1;
}

// ---------------- kvw: KWt[b][c][h*64+d] = sum_e kv[b,h,d,e] * Wproj[h*64+e][c] --
__global__ __launch_bounds__(256) void kvw(const float* __restrict__ kvg,
                                           const unsigned short* __restrict__ Bt2,
                                           unsigned short* __restrict__ KWt,
                                           int b0) {
  const int mt = blockIdx.x;                // c-tile (256 rows)
  const int h  = blockIdx.y;
  const int b  = b0 + blockIdx.z;
  const int t = threadIdx.x, l = t & 63, w = t >> 6;
  const int cb = mt * 256 + w * 64;
  f32x4 acc[4][4] = {};
  const float* kvh = kvg + (long)(b * HEADS + h) * 4096;
#pragma unroll
  for (int ks = 0; ks < 2; ++ks) {
    const int e0 = ks * 32 + (l >> 4) * 8;
    bf16x8 afr[4], bfq[4];
#pragma unroll
    for (int mi = 0; mi < 4; ++mi) {
      int c = cb + mi * 16 + (l & 15);
      afr[mi] = *(const bf16x8*)&Bt2[(long)c * 1024 + h * 64 + e0];
    }
#pragma unroll
    for (int ni = 0; ni < 4; ++ni) {
      int d = ni * 16 + (l & 15);
      const float* kp = &kvh[d * 64 + e0];
      bf16x8 bv;
#pragma unroll
      for (int j = 0; j < 8; ++j) bv[j] = (short)f2bf(kp[j]);
      bfq[ni] = bv;
    }
#pragma unroll
    for (int mi = 0; mi < 4; ++mi)
#pragma unroll
      for (int ni = 0; ni < 4; ++ni)
        acc[mi][ni] = MF(afr[mi], bfq[ni], acc[mi][ni]);
  }
  unsigned short* dst = KWt + (long)b * 1048576;
#pragma unroll
  for (int mi = 0; mi < 4; ++mi)
#pragma unroll
    for (int ni = 0; ni < 4; ++ni)
#pragma unroll
      for (int j = 0; j < 4; ++j) {
        int c = cb + mi * 16 + (l >> 4) * 4 + j;
        int d = ni * 16 + (l & 15);
        dst[(long)c * 1024 + h * 64 + d] = f2bf(acc[mi][ni][j]);
      }
}

// ---------------- launch ----------------

extern "C" void kernel_launch(void* const* d_in, const int* in_sizes, int n_in,
                              void* d_out, int out_size, void* d_ws, size_t ws_size,
                              hipStream_t stream) {
  const float* x     = (const float*)d_in[0];
  const float* Wqkv  = (const float*)d_in[1];
  const float* Wproj = (const float*)d_in[2];
  const float* bproj = (const float*)d_in[3];

  const size_t SZ_KV   = 4UL * HEADS * 64 * 64 * 4;   // 1,048,576
  const size_t SZ_KSUM = 4UL * HEADS * 64 * 4;        //    16,384
  const size_t SZ_BT2  = 1024UL * 1024 * 2;           // 2,097,152
  const size_t SZ_BT1  = 3072UL * 1024 * 2;           // 6,291,456
  const size_t SZ_KWT  = 4UL * 1024 * 1024 * 2;       // 8,388,608
  const size_t HEAD_SZ = SZ_KV + SZ_KSUM + SZ_BT2;    // 3,162,112

  int NB;
  if      (ws_size >= HEAD_SZ + 3UL * 16384 * 2048 + SZ_BT1)            NB = 1;
  else if (ws_size >= HEAD_SZ + 3UL * 8192 * 2048 + SZ_BT1 + SZ_KWT)    NB = 2;
  else if (ws_size >= HEAD_SZ + 3UL * 4096 * 2048 + SZ_BT1 + SZ_KWT)    NB = 4;
  else return;
  const int MCH = 16384 / NB;
  const size_t SZ_PLANE = (size_t)MCH * 2048;

  size_t off = 0;
  char* ws = (char*)d_ws;
  float*          kvg = (float*)(ws + off);          off += SZ_KV;
  float*          ksm = (float*)(ws + off);          off += SZ_KSUM;
  unsigned short* Bt2 = (unsigned short*)(ws + off); off += SZ_BT2;
  unsigned short* Ax  = (unsigned short*)(ws + off); off += SZ_PLANE;
  unsigned short* Kp  = (unsigned short*)(ws + off); off += SZ_PLANE;
  unsigned short* Bt1 = (unsigned short*)(ws + off); off += SZ_BT1;
  unsigned short* Vp  = (unsigned short*)(ws + off); off += SZ_PLANE;
  unsigned short* KWt = (NB == 1) ? Bt1               // Bt1+Vp dead by kvw time
                                  : (unsigned short*)(ws + off);

  hipMemsetAsync(kvg, 0, SZ_KV + SZ_KSUM, stream);

  conv_w<<<dim3(16, 48), 256, 0, stream>>>(Wqkv, Bt1, 3072);
  conv_w<<<dim3(16, 16), 256, 0, stream>>>(Wproj, Bt2, 1024);

  for (int c = 0; c < NB; ++c) {
    const long row0 = (long)c * MCH;
    const float* xc = x + row0 * 1024;
    float* outc = (float*)d_out + row0 * 1024;
    unsigned short* Qp = (unsigned short*)outc;   // dead region until gemm2(c)
    const int b0 = (int)(row0 / 4096);

    conv_x<<<dim3(MCH), 256, 0, stream>>>(xc, Ax);
    gemm8<0><<<dim3(12, MCH / 256), 512, 0, stream>>>(Ax, Bt1, Qp, Kp, Vp,
                                                      nullptr, nullptr, 0L);
    attn_kv<<<dim3(4 * (MCH / 4096), HEADS), 256, 0, stream>>>(Kp, Vp, kvg, ksm, b0);
    qz_scale<<<dim3(MCH / 4), 256, 0, stream>>>(Qp, ksm, Ax, b0);
    kvw<<<dim3(4, HEADS, MCH / 4096), 256, 0, stream>>>(kvg, Bt2, KWt, b0);
    gemm8<1><<<dim3(4, MCH / 256), 512, 0, stream>>>(
        Ax, KWt + (long)b0 * 1048576, nullptr, nullptr, nullptr,
        outc, bproj, 1048576L);
  }
}

// Round 7
// 324.381 us; speedup vs baseline: 2.4404x; 1.0122x over previous
//
#include <hip/hip_runtime.h>
#include <hip/hip_bf16.h>

// LinAtten: x[4,4096,1024] -> qkv GEMM -> elu+1 -> linear attention -> proj GEMM.
// bf16 MFMA GEMMs on the 256^2 8-phase schedule (T2 swizzle, counted vmcnt,
// setprio) + T1 XCD-chunked block swizzle. Attention tail reassociated:
//   out = (z .* q) @ KW_b + bias,  KW_b = blockdiag(kv_b) @ Wproj
// K,V planes written TRANSPOSED [bl][h][d][n] so attn_kv is a pure MFMA GEMM.

#define DIM    1024
#define HEADS  16
#define SEQ    4096

typedef __attribute__((ext_vector_type(8))) short bf16x8;
typedef __attribute__((ext_vector_type(4))) float f32x4;

__device__ __forceinline__ unsigned short f2bf(float f) {
  unsigned u = __float_as_uint(f);
  u += 0x7fffu + ((u >> 16) & 1u);          // RNE
  return (unsigned short)(u >> 16);
}
__device__ __forceinline__ float bf2f(unsigned short h) {
  return __uint_as_float((unsigned)h << 16);
}
__device__ __forceinline__ void gload_lds16(const void* g, void* l) {
  __builtin_amdgcn_global_load_lds((const __attribute__((address_space(1))) void*)g,
                                   (__attribute__((address_space(3))) void*)l, 16, 0, 0);
}

// ---------------- conversions ----------------

__global__ __launch_bounds__(256) void conv_x(const float* __restrict__ x,
                                              unsigned short* __restrict__ Ax) {
  int idx = blockIdx.x * 256 + threadIdx.x;       // float4 index
  float4 v = ((const float4*)x)[idx];
  ushort4 h;
  h.x = f2bf(v.x); h.y = f2bf(v.y); h.z = f2bf(v.z); h.w = f2bf(v.w);
  ((ushort4*)Ax)[idx] = h;
}

// fused W transpose: y<48 -> Wqkv[1024,3072]->Bt1 ; y>=48 -> Wproj[1024,1024]->Bt2
__global__ __launch_bounds__(256) void conv_w2(const float* __restrict__ Wqkv,
                                               const float* __restrict__ Wproj,
                                               unsigned short* __restrict__ Bt1,
                                               unsigned short* __restrict__ Bt2) {
  __shared__ float tile[64][65];
  const bool second = blockIdx.y >= 48;
  const float* W = second ? Wproj : Wqkv;
  unsigned short* Bt = second ? Bt2 : Bt1;
  const int Ncols = second ? 1024 : 3072;
  const int kk0 = blockIdx.x * 64;
  const int c0  = (second ? (blockIdx.y - 48) : blockIdx.y) * 64;
  const int t = threadIdx.x;
  const int cl = t & 63, kl = t >> 6;
#pragma unroll
  for (int i = 0; i < 16; ++i)
    tile[kl + i * 4][cl] = W[(long)(kk0 + kl + i * 4) * Ncols + c0 + cl];
  __syncthreads();
#pragma unroll
  for (int i = 0; i < 16; ++i) {
    int c = kl + i * 4;
    Bt[(long)(c0 + c) * 1024 + kk0 + cl] = f2bf(tile[cl][c]);
  }
}

// ---------------- 256^2 8-phase bf16 GEMM --------------------------------------

__device__ __forceinline__ void stage_half(const unsigned short* srcBase, long rowOff,
                                           int kt, unsigned short* ldsBase, int t) {
  const unsigned short* s0 = srcBase + rowOff + (long)kt * 64;
  gload_lds16(s0, ldsBase + t * 8);                      // rows H*128 + 0..63
  gload_lds16(s0 + 64 * 1024, ldsBase + 4096 + t * 8);   // rows H*128 + 64..127
}

#define MF(a, b, c) __builtin_amdgcn_mfma_f32_16x16x32_bf16(a, b, c, 0, 0, 0)

#define PHASE(P, qd, READB, STAGE, WAIT)                                          \
  {                                                                               \
    const unsigned short* ab = &lds[(P) * 32768 + abase + (qd) * 2048];           \
    bf16x8 a00 = *(const bf16x8*)(ab + sl0);                                      \
    bf16x8 a01 = *(const bf16x8*)(ab + sl1);                                      \
    bf16x8 a10 = *(const bf16x8*)(ab + 1024 + sl0);                               \
    bf16x8 a11 = *(const bf16x8*)(ab + 1024 + sl1);                               \
    if (READB) {                                                                  \
      const unsigned short* bb = &lds[(P) * 32768 + 16384 + bbase];               \
      bfr[0][0] = *(const bf16x8*)(bb + sl0);                                     \
      bfr[0][1] = *(const bf16x8*)(bb + sl1);                                     \
      bfr[1][0] = *(const bf16x8*)(bb + 1024 + sl0);                              \
      bfr[1][1] = *(const bf16x8*)(bb + 1024 + sl1);                              \
      bfr[2][0] = *(const bf16x8*)(bb + 2048 + sl0);                              \
      bfr[2][1] = *(const bf16x8*)(bb + 2048 + sl1);                              \
      bfr[3][0] = *(const bf16x8*)(bb + 3072 + sl0);                              \
      bfr[3][1] = *(const bf16x8*)(bb + 3072 + sl1);                              \
    }                                                                             \
    STAGE;                                                                        \
    WAIT;                                                                         \
    asm volatile("s_barrier" ::: "memory");                                       \
    __builtin_amdgcn_s_setprio(1);                                                \
    acc[(qd)*2][0] = MF(a00, bfr[0][0], acc[(qd)*2][0]);                          \
    acc[(qd)*2][1] = MF(a00, bfr[1][0], acc[(qd)*2][1]);                          \
    acc[(qd)*2][2] = MF(a00, bfr[2][0], acc[(qd)*2][2]);                          \
    acc[(qd)*2][3] = MF(a00, bfr[3][0], acc[(qd)*2][3]);                          \
    acc[(qd)*2][0] = MF(a01, bfr[0][1], acc[(qd)*2][0]);                          \
    acc[(qd)*2][1] = MF(a01, bfr[1][1], acc[(qd)*2][1]);                          \
    acc[(qd)*2][2] = MF(a01, bfr[2][1], acc[(qd)*2][2]);                          \
    acc[(qd)*2][3] = MF(a01, bfr[3][1], acc[(qd)*2][3]);                          \
    acc[(qd)*2+1][0] = MF(a10, bfr[0][0], acc[(qd)*2+1][0]);                      \
    acc[(qd)*2+1][1] = MF(a10, bfr[1][0], acc[(qd)*2+1][1]);                      \
    acc[(qd)*2+1][2] = MF(a10, bfr[2][0], acc[(qd)*2+1][2]);                      \
    acc[(qd)*2+1][3] = MF(a10, bfr[3][0], acc[(qd)*2+1][3]);                      \
    acc[(qd)*2+1][0] = MF(a11, bfr[0][1], acc[(qd)*2+1][0]);                      \
    acc[(qd)*2+1][1] = MF(a11, bfr[1][1], acc[(qd)*2+1][1]);                      \
    acc[(qd)*2+1][2] = MF(a11, bfr[2][1], acc[(qd)*2+1][2]);                      \
    acc[(qd)*2+1][3] = MF(a11, bfr[3][1], acc[(qd)*2+1][3]);                      \
    __builtin_amdgcn_s_setprio(0);                                                \
    asm volatile("s_barrier" ::: "memory");                                       \
  }

#define VM4 asm volatile("s_waitcnt vmcnt(4)" ::: "memory")
#define VM0 asm volatile("s_waitcnt vmcnt(0)" ::: "memory")

// EPI 0: q plane row-major [n][1024] (elu+1); k,v planes TRANSPOSED
//        [bl][h][d][4096] (elu+1 on k only).  EPI 1: +bias, f32, per-batch B.
template <int EPI>
__global__ __launch_bounds__(512) void gemm8(const unsigned short* __restrict__ A,
                                             const unsigned short* __restrict__ Bt,
                                             unsigned short* __restrict__ P0,
                                             unsigned short* __restrict__ P1,
                                             unsigned short* __restrict__ P2,
                                             float* __restrict__ Cf,
                                             const float* __restrict__ bias,
                                             long bstride) {
  __shared__ unsigned short lds[65536];     // 128 KiB
  const int t = threadIdx.x;
  const int l = t & 63, w = t >> 6;
  const int wr = w >> 2, wc = w & 3;        // 2x4 wave grid

  // T1: bijective XCD-chunked swizzle (nwg % 8 == 0 in all configs).
  // Each XCD owns contiguous (m-row x all-c) chunks -> A-panels fetched once
  // per owning XCD; B stays L2-resident per XCD.
  const int gx = gridDim.x;
  const int nwg = gx * gridDim.y;
  int bid = blockIdx.y * gx + blockIdx.x;
  bid = (bid & 7) * (nwg >> 3) + (bid >> 3);
  const int m0 = (bid / gx) * 256;
  const int c0 = (bid % gx) * 256;

  f32x4 acc[8][4] = {};
  bf16x8 bfr[4][2];

  const int sl0 = (((l >> 4)) ^ (l & 7)) * 8;
  const int sl1 = ((4 + (l >> 4)) ^ (l & 7)) * 8;
  const int abase = wr * 8192 + (l & 15) * 64;
  const int bbase = (wc >> 1) * 8192 + (wc & 1) * 4096 + (l & 15) * 64;

  const int sw = ((t & 7) ^ ((t >> 3) & 7)) * 8;
  const unsigned short* srcA = A + (long)(m0 + (t >> 3)) * 1024 + sw;
  const unsigned short* srcB = Bt + (long)(m0 >> 12) * bstride +
                               (long)(c0 + (t >> 3)) * 1024 + sw;
  const long H1 = 128L * 1024;

  unsigned short* A0h0 = &lds[0];      unsigned short* A0h1 = &lds[8192];
  unsigned short* B0h0 = &lds[16384];  unsigned short* B0h1 = &lds[24576];
  unsigned short* A1h0 = &lds[32768];  unsigned short* A1h1 = &lds[40960];
  unsigned short* B1h0 = &lds[49152];  unsigned short* B1h1 = &lds[57344];

  stage_half(srcA, 0,  0, A0h0, t);  stage_half(srcA, H1, 0, A0h1, t);
  stage_half(srcB, 0,  0, B0h0, t);  stage_half(srcB, H1, 0, B0h1, t);
  stage_half(srcB, 0,  1, B1h0, t);  stage_half(srcB, H1, 1, B1h1, t);
  VM4;
  asm volatile("s_barrier" ::: "memory");

  for (int it = 0; it < 7; ++it) {
    const int k1 = 2 * it + 1, k2 = 2 * it + 2, k3 = 2 * it + 3;
    PHASE(0, 0, 1, stage_half(srcA, 0,  k1, A1h0, t), );
    PHASE(0, 1, 0, stage_half(srcA, H1, k1, A1h1, t), );
    PHASE(0, 2, 0, stage_half(srcB, 0,  k2, B0h0, t), );
    PHASE(0, 3, 0, stage_half(srcB, H1, k2, B0h1, t), VM4);
    PHASE(1, 0, 1, stage_half(srcA, 0,  k2, A0h0, t), );
    PHASE(1, 1, 0, stage_half(srcA, H1, k2, A0h1, t), );
    PHASE(1, 2, 0, stage_half(srcB, 0,  k3, B1h0, t), );
    PHASE(1, 3, 0, stage_half(srcB, H1, k3, B1h1, t), VM4);
  }
  PHASE(0, 0, 1, stage_half(srcA, 0,  15, A1h0, t), );
  PHASE(0, 1, 0, stage_half(srcA, H1, 15, A1h1, t), );
  PHASE(0, 2, 0, , );
  PHASE(0, 3, 0, , VM0);
  PHASE(1, 0, 1, , );
  PHASE(1, 1, 0, , );
  PHASE(1, 2, 0, , );
  PHASE(1, 3, 0, , );

  const int rowb = m0 + wr * 128 + (l >> 4) * 4;
  if (EPI == 0) {
    const int cwb = c0 + wc * 64;
    const int plane = cwb >> 10;            // wave-uniform (0=q,1=k,2=v)
    if (plane == 0) {
      const int ccb = (cwb & 1023) + (l & 15);
#pragma unroll
      for (int fm = 0; fm < 8; ++fm)
#pragma unroll
        for (int fn = 0; fn < 4; ++fn)
#pragma unroll
          for (int j = 0; j < 4; ++j) {
            int r = rowb + fm * 16 + j;
            float v = acc[fm][fn][j];
            v = (v > 0.f) ? v + 1.f : __expf(v);            // elu + 1
            P0[(long)r * 1024 + ccb + fn * 16] = f2bf(v);
          }
    } else {
      unsigned short* P = (plane == 1) ? P1 : P2;
      const int ccb = (cwb & 1023) + (l & 15);
#pragma unroll
      for (int fm = 0; fm < 8; ++fm) {
        const int n0 = rowb + fm * 16;                      // chunk-local row
        const int bl = n0 >> 12, np = n0 & 4095;
#pragma unroll
        for (int fn = 0; fn < 4; ++fn) {
          const int cc = ccb + fn * 16;                     // 0..1023
          const int h = cc >> 6, d = cc & 63;
          ushort4 o;
#pragma unroll
          for (int j = 0; j < 4; ++j) {
            float v = acc[fm][fn][j];
            if (plane == 1) v = (v > 0.f) ? v + 1.f : __expf(v);   // elu + 1 (k)
            ((unsigned short*)&o)[j] = f2bf(v);
          }
          *(ushort4*)&P[((long)(bl * 16 + h) * 64 + d) * 4096 + np] = o;
        }
      }
    }
  } else {
    const int cb = c0 + wc * 64 + (l & 15);
#pragma unroll
    for (int fm = 0; fm < 8; ++fm)
#pragma unroll
      for (int fn = 0; fn < 4; ++fn) {
        float bs = bias[cb + fn * 16];
#pragma unroll
        for (int j = 0; j < 4; ++j) {
          int r = rowb + fm * 16 + j;
          Cf[(long)r * 1024 + cb + fn * 16] = acc[fm][fn][j] + bs;
        }
      }
  }
}

// ---------------- attention pass 1 (MFMA): kv[b,h,d,e], ksum[b,h,d] ------------
// Kt,Vt: [bl][h][64 d][4096 n] bf16. Grid (4*nbatch, HEADS); block = 4 waves,
// wave w covers 256 n. Fragments straight from global (L2/L3-hot).
__global__ __launch_bounds__(256) void attn_kv(const unsigned short* __restrict__ Kt,
                                               const unsigned short* __restrict__ Vt,
                                               float* __restrict__ kvg,
                                               float* __restrict__ ksumg, int b0) {
  const int bl = blockIdx.x >> 2, cx = blockIdx.x & 3;
  const int h = blockIdx.y;
  const int b = b0 + bl;
  const int t = threadIdx.x, l = t & 63, w = t >> 6;
  const long pbase = ((long)(bl * HEADS + h) * 64) * 4096;
  const unsigned short* kb = Kt + pbase;
  const unsigned short* vb = Vt + pbase;

  f32x4 acc[4][4] = {};
  f32x4 ks[4] = {};
  bf16x8 ones;
#pragma unroll
  for (int j = 0; j < 8; ++j) ones[j] = (short)0x3F80;    // bf16 1.0

  const int lr = l & 15;
  for (int s = 0; s < 8; ++s) {
    const int n0 = cx * 1024 + w * 256 + s * 32 + (l >> 4) * 8;
    bf16x8 af[4], bfq[4];
#pragma unroll
    for (int dt = 0; dt < 4; ++dt)
      af[dt] = *(const bf16x8*)&kb[(long)(dt * 16 + lr) * 4096 + n0];
#pragma unroll
    for (int et = 0; et < 4; ++et)
      bfq[et] = *(const bf16x8*)&vb[(long)(et * 16 + lr) * 4096 + n0];
#pragma unroll
    for (int dt = 0; dt < 4; ++dt) {
#pragma unroll
      for (int et = 0; et < 4; ++et)
        acc[dt][et] = MF(af[dt], bfq[et], acc[dt][et]);
      ks[dt] = MF(af[dt], ones, ks[dt]);
    }
  }

  // C layout: row d = dt*16 + (l>>4)*4 + j, col e = et*16 + (l&15)
  float* kvdst = kvg + (long)(b * HEADS + h) * 4096;
#pragma unroll
  for (int dt = 0; dt < 4; ++dt)
#pragma unroll
    for (int et = 0; et < 4; ++et)
#pragma unroll
      for (int j = 0; j < 4; ++j)
        atomicAdd(&kvdst[(dt * 16 + (l >> 4) * 4 + j) * 64 + et * 16 + lr],
                  acc[dt][et][j]);
  if (lr == 0) {
    float* ksdst = ksumg + (long)(b * HEADS + h) * 64;
#pragma unroll
    for (int dt = 0; dt < 4; ++dt)
#pragma unroll
      for (int j = 0; j < 4; ++j)
        atomicAdd(&ksdst[dt * 16 + (l >> 4) * 4 + j], ks[dt][j]);
  }
}

// ---------------- qz_scale: Aq[n][c] = q[n][c] / (q[n,h,:].ksum[b,h,:] + 1e-6) --
__global__ __launch_bounds__(256) void qz_scale(const unsigned short* __restrict__ Qp,
                                                const float* __restrict__ ksumg,
                                                unsigned short* __restrict__ Aq,
                                                int b0) {
  __shared__ float ks_lds[1024];
  const int t = threadIdx.x, l = t & 63, w = t >> 6;
  const int blk = blockIdx.x;
  const int b = b0 + (blk >> 10);           // 1024 blocks per batch
  ((float4*)ks_lds)[t] = ((const float4*)(ksumg + (long)b * 1024))[t];
  __syncthreads();
  const long base = (long)(blk * 4 + w) * 1024 + l * 16;
  bf16x8 v0 = *(const bf16x8*)&Qp[base];
  bf16x8 v1 = *(const bf16x8*)&Qp[base + 8];
  float qf[16];
#pragma unroll
  for (int j = 0; j < 8; ++j) {
    qf[j]     = bf2f((unsigned short)v0[j]);
    qf[8 + j] = bf2f((unsigned short)v1[j]);
  }
  const float* ks = &ks_lds[(l >> 2) * 64 + (l & 3) * 16];
  float den = 0.f;
#pragma unroll
  for (int j = 0; j < 16; ++j) den = fmaf(qf[j], ks[j], den);
  den += __shfl_xor(den, 1);
  den += __shfl_xor(den, 2);
  const float z = 1.f / (den + 1e-6f);
#pragma unroll
  for (int j = 0; j < 8; ++j) {
    v0[j] = (short)f2bf(qf[j] * z);
    v1[j] = (short)f2bf(qf[8 + j] * z);
  }
  *(bf16x8*)&Aq[base] = v0;
  *(bf16x8*)&Aq[base + 8] = v1;
}

// ---------------- kvw: KWt[b][c][h*64+d] = sum_e kv[b,h,d,e] * Wproj[h*64+e][c] --
__global__ __launch_bounds__(256) void kvw(const float* __restrict__ kvg,
                                           const unsigned short* __restrict__ Bt2,
                                           unsigned short* __restrict__ KWt,
                                           int b0) {
  const int mt = blockIdx.x;                // c-tile (256 rows)
  const int h  = blockIdx.y;
  const int b  = b0 + blockIdx.z;
  const int t = threadIdx.x, l = t & 63, w = t >> 6;
  const int cb = mt * 256 + w * 64;
  f32x4 acc[4][4] = {};
  const float* kvh = kvg + (long)(b * HEADS + h) * 4096;
#pragma unroll
  for (int ks = 0; ks < 2; ++ks) {
    const int e0 = ks * 32 + (l >> 4) * 8;
    bf16x8 afr[4], bfq[4];
#pragma unroll
    for (int mi = 0; mi < 4; ++mi) {
      int c = cb + mi * 16 + (l & 15);
      afr[mi] = *(const bf16x8*)&Bt2[(long)c * 1024 + h * 64 + e0];
    }
#pragma unroll
    for (int ni = 0; ni < 4; ++ni) {
      int d = ni * 16 + (l & 15);
      const float* kp = &kvh[d * 64 + e0];
      bf16x8 bv;
#pragma unroll
      for (int j = 0; j < 8; ++j) bv[j] = (short)f2bf(kp[j]);
      bfq[ni] = bv;
    }
#pragma unroll
    for (int mi = 0; mi < 4; ++mi)
#pragma unroll
      for (int ni = 0; ni < 4; ++ni)
        acc[mi][ni] = MF(afr[mi], bfq[ni], acc[mi][ni]);
  }
  unsigned short* dst = KWt + (long)b * 1048576;
#pragma unroll
  for (int mi = 0; mi < 4; ++mi)
#pragma unroll
    for (int ni = 0; ni < 4; ++ni)
#pragma unroll
      for (int j = 0; j < 4; ++j) {
        int c = cb + mi * 16 + (l >> 4) * 4 + j;
        int d = ni * 16 + (l & 15);
        dst[(long)c * 1024 + h * 64 + d] = f2bf(acc[mi][ni][j]);
      }
}

// ---------------- launch ----------------

extern "C" void kernel_launch(void* const* d_in, const int* in_sizes, int n_in,
                              void* d_out, int out_size, void* d_ws, size_t ws_size,
                              hipStream_t stream) {
  const float* x     = (const float*)d_in[0];
  const float* Wqkv  = (const float*)d_in[1];
  const float* Wproj = (const float*)d_in[2];
  const float* bproj = (const float*)d_in[3];

  const size_t SZ_KV   = 4UL * HEADS * 64 * 64 * 4;   // 1,048,576
  const size_t SZ_KSUM = 4UL * HEADS * 64 * 4;        //    16,384
  const size_t SZ_BT2  = 1024UL * 1024 * 2;           // 2,097,152
  const size_t SZ_BT1  = 3072UL * 1024 * 2;           // 6,291,456
  const size_t SZ_KWT  = 4UL * 1024 * 1024 * 2;       // 8,388,608
  const size_t HEAD_SZ = SZ_KV + SZ_KSUM + SZ_BT2;    // 3,162,112

  int NB;
  if      (ws_size >= HEAD_SZ + 3UL * 16384 * 2048 + SZ_BT1)            NB = 1;
  else if (ws_size >= HEAD_SZ + 3UL * 8192 * 2048 + SZ_BT1 + SZ_KWT)    NB = 2;
  else if (ws_size >= HEAD_SZ + 3UL * 4096 * 2048 + SZ_BT1 + SZ_KWT)    NB = 4;
  else return;
  const int MCH = 16384 / NB;
  const size_t SZ_PLANE = (size_t)MCH * 2048;

  size_t off = 0;
  char* ws = (char*)d_ws;
  float*          kvg = (float*)(ws + off);          off += SZ_KV;
  float*          ksm = (float*)(ws + off);          off += SZ_KSUM;
  unsigned short* Bt2 = (unsigned short*)(ws + off); off += SZ_BT2;
  unsigned short* Ax  = (unsigned short*)(ws + off); off += SZ_PLANE;
  unsigned short* Kp  = (unsigned short*)(ws + off); off += SZ_PLANE;
  unsigned short* Bt1 = (unsigned short*)(ws + off); off += SZ_BT1;
  unsigned short* Vp  = (unsigned short*)(ws + off); off += SZ_PLANE;
  unsigned short* KWt = (NB == 1) ? Bt1               // Bt1+Vp dead by kvw time
                                  : (unsigned short*)(ws + off);

  hipMemsetAsync(kvg, 0, SZ_KV + SZ_KSUM, stream);

  conv_w2<<<dim3(16, 64), 256, 0, stream>>>(Wqkv, Wproj, Bt1, Bt2);

  for (int c = 0; c < NB; ++c) {
    const long row0 = (long)c * MCH;
    const float* xc = x + row0 * 1024;
    float* outc = (float*)d_out + row0 * 1024;
    unsigned short* Qp = (unsigned short*)outc;   // dead region until gemm2(c)
    const int b0 = (int)(row0 / 4096);

    conv_x<<<dim3(MCH), 256, 0, stream>>>(xc, Ax);
    gemm8<0><<<dim3(12, MCH / 256), 512, 0, stream>>>(Ax, Bt1, Qp, Kp, Vp,
                                                      nullptr, nullptr, 0L);
    attn_kv<<<dim3(4 * (MCH / 4096), HEADS), 256, 0, stream>>>(Kp, Vp, kvg, ksm, b0);
    qz_scale<<<dim3(MCH / 4), 256, 0, stream>>>(Qp, ksm, Ax, b0);
    kvw<<<dim3(4, HEADS, MCH / 4096), 256, 0, stream>>>(kvg, Bt2, KWt, b0);
    gemm8<1><<<dim3(4, MCH / 256), 512, 0, stream>>>(
        Ax, KWt + (long)b0 * 1048576, nullptr, nullptr, nullptr,
        outc, bproj, 1048576L);
  }
}